// Round 10
// baseline (486.809 us; speedup 1.0000x reference)
//
#include <hip/hip_runtime.h>
#include <hip/hip_bf16.h>
#include <math.h>

#define D 256
#define NH 8
#define DH 32
#define LYR 2
#define G 64
#define KK 4096
#define T 4
#define EC 32
#define B 4
#define N 512
#define CITY 256
#define DFF 1024
#define NS 513    // N + 1 bs token
#define NSP 544   // 17 * 32 padded token count
#define MSRC 2052 // B * NS
#define MSRCP 2176 // padded to 34*64
#define ISQ 0.17677669529663687f
#define LOG2E 1.4426950408889634f

typedef short bf16x8 __attribute__((ext_vector_type(8)));
typedef float f32x4 __attribute__((ext_vector_type(4)));

// gelu via exact identity 0.5*(1+tanh(u)) == sigmoid(2u); exp2+rcp, ~7 VALU vs libm tanhf
__device__ __forceinline__ float gelu_f(float x) {
    const float c2 = 2.f * 0.7978845608028654f * LOG2E;  // 2*c*log2e
    float u = x + 0.044715f * x * x * x;
    float e = __builtin_amdgcn_exp2f(-c2 * u);
    return x * __builtin_amdgcn_rcpf(1.f + e);
}

__device__ __forceinline__ unsigned short f2bf(float f) {
    unsigned int u = __float_as_uint(f);
    unsigned int r = (u + 0x7FFFu + ((u >> 16) & 1u)) >> 16;
    return (unsigned short)r;
}

__device__ __forceinline__ float bf2f(unsigned short u) {
    return __uint_as_float((unsigned)u << 16);
}

__device__ __forceinline__ unsigned cvtpk(float a, float b) {
    unsigned r;
    asm("v_cvt_pk_bf16_f32 %0, %1, %2" : "=v"(r) : "v"(a), "v"(b));
    return r;
}

__device__ __forceinline__ void gl2lds16(const unsigned short* g, unsigned short* l) {
    __builtin_amdgcn_global_load_lds(
        (const __attribute__((address_space(1))) unsigned int*)g,
        (__attribute__((address_space(3))) unsigned int*)l, 16, 0, 0);
}

// ================= pre1: transposes + tok_mlp + density + conv1 + tvec + K/V pad zero ===========
__global__ __launch_bounds__(256) void pre1_k(
    const float* __restrict__ wq, const float* __restrict__ wk,
    const float* __restrict__ wv, const float* __restrict__ wo,
    const float* __restrict__ ff1, const float* __restrict__ ff2,
    const float* __restrict__ tfp,
    const float* __restrict__ bk, const float* __restrict__ bv,
    unsigned short* __restrict__ wqT, unsigned short* __restrict__ kvT,
    unsigned short* __restrict__ woT, unsigned short* __restrict__ ff1T,
    unsigned short* __restrict__ ff2T, unsigned short* __restrict__ tfpT,
    float* __restrict__ kvbias,
    const float* __restrict__ meas_xy, const float* __restrict__ meas_v,
    const float* __restrict__ bs_xy,
    const float* __restrict__ mp_w1, const float* __restrict__ mp_b1,
    const float* __restrict__ mp_w2, const float* __restrict__ mp_b2,
    const float* __restrict__ bp_w1, const float* __restrict__ bp_b1,
    const float* __restrict__ bp_w2, const float* __restrict__ bp_b2,
    unsigned short* __restrict__ srcbf, float* __restrict__ src_xy,
    float* __restrict__ dens,
    const float* __restrict__ city, const float* __restrict__ env_w1,
    const float* __restrict__ env_b1, float* __restrict__ h1,
    const float* __restrict__ task_emb, const int* __restrict__ task_id,
    const float* __restrict__ tp_w, const float* __restrict__ tp_b,
    float* __restrict__ tvec,
    unsigned short* __restrict__ khd, unsigned short* __restrict__ vch)
{
    __shared__ float sh[1088];
    int bx = blockIdx.x;
    int tid = threadIdx.x;
    if (bx < 1792) {
        const float* src; unsigned short* dst;
        int Kd, Nn, nmat, rowOff = 0, t; size_t matStride;
        if (bx < 512) {
            int job = bx >> 7; t = bx & 127;
            Kd = 256; Nn = 256; nmat = 2;
            if (job == 0)      { src = wq; dst = wqT; matStride = 65536; }
            else if (job == 1) { src = wk; dst = kvT; matStride = 131072; }
            else if (job == 2) { src = wv; dst = kvT; matStride = 131072; rowOff = 256; }
            else               { src = wo; dst = woT; matStride = 65536; }
            if ((t & 63) == 0 && job == 1) kvbias[(t >> 6) * 512 + tid] = bk[(t >> 6) * 256 + tid];
            if ((t & 63) == 0 && job == 2) kvbias[(t >> 6) * 512 + 256 + tid] = bv[(t >> 6) * 256 + tid];
        } else if (bx < 1024) { t = bx - 512;  src = ff1; dst = ff1T; Kd = 256;  Nn = 1024; nmat = 2; matStride = 262144; }
        else if (bx < 1536)   { t = bx - 1024; src = ff2; dst = ff2T; Kd = 1024; Nn = 256;  nmat = 2; matStride = 262144; }
        else                  { t = bx - 1536; src = tfp; dst = tfpT; Kd = 256;  Nn = 256;  nmat = 4; matStride = 65536; }
        int tn = Nn / 32, perMat = tn * (Kd / 32);
        int mat = t / perMat;
        int rem = t - mat * perMat;
        int nb = (rem % tn) * 32, kb = (rem / tn) * 32;
        const float* s = src + (size_t)mat * Kd * Nn;
        unsigned short* d = dst + (size_t)mat * matStride;
        float (*tb)[33] = (float (*)[33])sh;
        int tx = tid & 31, ty = tid >> 5;
        #pragma unroll
        for (int i = 0; i < 4; i++)
            tb[ty + i * 8][tx] = s[(size_t)(kb + ty + i * 8) * Nn + nb + tx];
        __syncthreads();
        #pragma unroll
        for (int i = 0; i < 4; i++)
            d[(size_t)(rowOff + nb + ty + i * 8) * Kd + kb + tx] = f2bf(tb[tx][ty + i * 8]);
    } else if (bx < 3968) {
        int id = bx - 1792;
        int dd = tid;
        if (id >= B * N + B) {
            srcbf[(size_t)id * D + dd] = 0;
            return;
        }
        float* hid = sh;
        int row;
        const float *w1, *b1, *w2, *b2;
        float x0, x1, x2 = 0.f;
        int nin;
        if (id < B * N) {
            int b = id >> 9, n = id & 511;
            x0 = meas_xy[(b * N + n) * 2 + 0];
            x1 = meas_xy[(b * N + n) * 2 + 1];
            x2 = meas_v[b * N + n];
            w1 = mp_w1; b1 = mp_b1; w2 = mp_w2; b2 = mp_b2; nin = 3;
            row = b * NS + n;
        } else {
            int b = id - B * N;
            x0 = bs_xy[b * 2 + 0];
            x1 = bs_xy[b * 2 + 1];
            w1 = bp_w1; b1 = bp_b1; w2 = bp_w2; b2 = bp_b2; nin = 2;
            row = b * NS + N;
        }
        float h = x0 * w1[dd] + x1 * w1[D + dd] + b1[dd];
        if (nin == 3) h += x2 * w1[2 * D + dd];
        hid[dd] = gelu_f(h);
        __syncthreads();
        float o = b2[dd];
        for (int j = 0; j < D; j++) o += hid[j] * w2[j * D + dd];
        srcbf[(size_t)row * D + dd] = f2bf(o);
        if (dd == 0) { src_xy[row * 2 + 0] = x0; src_xy[row * 2 + 1] = x1; }
    } else if (bx < 4032) {
        int blk = bx - 3968;
        int b = blk >> 4, kc = blk & 15;
        int k = kc * 256 + tid;
        float* mx = sh; float* my = sh + 512;
        for (int i = tid; i < N; i += 256) {
            mx[i] = meas_xy[(b * N + i) * 2 + 0];
            my[i] = meas_xy[(b * N + i) * 2 + 1];
        }
        __syncthreads();
        float gx = ((k & 63) + 0.5f) / 64.f;
        float gy = ((k >> 6) + 0.5f) / 64.f;
        float s = 0.f;
        for (int n = 0; n < N; n++) {
            float dx = gx - mx[n], dy = gy - my[n];
            s += __expf(-(dx * dx + dy * dy) * 78.125f);
        }
        dens[b * KK + k] = s * (1.f / (float)N);
    } else if (bx < 6080) {
        int i = (bx - 4032) * 256 + tid;
        int x = i & 63, y = (i >> 6) & 63, c = (i >> 12) & 31, b = i >> 17;
        float s = env_b1[c];
        for (int ky = 0; ky < 3; ky++) {
            int yy = y + ky - 1;
            if (yy < 0 || yy >= G) continue;
            for (int kx = 0; kx < 3; kx++) {
                int xx = x + kx - 1;
                if (xx < 0 || xx >= G) continue;
                s += city[(b * CITY + yy * 4) * CITY + xx * 4] * env_w1[c * 9 + ky * 3 + kx];
            }
        }
        h1[i] = gelu_f(s);
    } else if (bx < 6084) {
        int b = bx - 6080;
        float* e = sh;
        e[tid] = task_emb[task_id[b] * D + tid];
        __syncthreads();
        float s = tp_b[tid];
        for (int j = 0; j < D; j++) s += e[j] * tp_w[j * D + tid];
        tvec[b * D + tid] = s;
    } else {
        int bh = bx - 6084;     // 0..31
        unsigned short* kp = khd + ((size_t)bh * 544 + 513) * 32;
        for (int i = tid; i < 992; i += 256) kp[i] = 0;
        unsigned short* vp = vch + ((size_t)bh * 17 + 16) * 1024;
        for (int i = tid; i < 1024; i += 256) vp[i] = 0;
    }
}

// ================= conv2: branchless, 4 c_out/thread, ci-pipelined =================
__global__ __launch_bounds__(256) void conv2_k(
    const float* __restrict__ h1, const float* __restrict__ w,
    const float* __restrict__ bias, float* __restrict__ h2) {
    int blk = blockIdx.x;
    int yt = blk & 15, cg = (blk >> 4) & 7, b = blk >> 7;
    int x = threadIdx.x & 63, y = yt * 4 + (threadIdx.x >> 6);
    int c0 = cg * 4;
    float flag[9];
    int off[9];
    #pragma unroll
    for (int ky = 0; ky < 3; ky++) {
        int yy = y + ky - 1;
        bool vy = (yy >= 0 && yy < G);
        int yc = min(max(yy, 0), G - 1);
        #pragma unroll
        for (int kx = 0; kx < 3; kx++) {
            int xx = x + kx - 1;
            bool vx = (xx >= 0 && xx < G);
            int xc = min(max(xx, 0), G - 1);
            flag[ky * 3 + kx] = (vy && vx) ? 1.f : 0.f;
            off[ky * 3 + kx] = yc * G + xc;
        }
    }
    const float* hp = h1 + ((size_t)(b * EC) << 12);
    float acc[4] = {bias[c0], bias[c0 + 1], bias[c0 + 2], bias[c0 + 3]};
    float v[9], nv[9];
    #pragma unroll
    for (int t = 0; t < 9; t++) v[t] = hp[off[t]] * flag[t];
    for (int ci = 0; ci < EC; ci++) {
        if (ci < EC - 1) {
            const float* hn = hp + ((size_t)(ci + 1) << 12);
            #pragma unroll
            for (int t = 0; t < 9; t++) nv[t] = hn[off[t]] * flag[t];
        }
        #pragma unroll
        for (int cc = 0; cc < 4; cc++) {
            const float* wp = w + ((size_t)(c0 + cc) * EC + ci) * 9;
            #pragma unroll
            for (int t = 0; t < 9; t++) acc[cc] += v[t] * wp[t];
        }
        #pragma unroll
        for (int t = 0; t < 9; t++) v[t] = nv[t];
    }
    size_t obase = (((size_t)(b * EC + c0)) << 12) + y * G + x;
    #pragma unroll
    for (int cc = 0; cc < 4; cc++)
        h2[obase + ((size_t)cc << 12)] = gelu_f(acc[cc]);
}

// ================= pre2: grid_init + out_init (nd bias computed in attn) =================
__global__ __launch_bounds__(256) void pre2_k(
    const float* __restrict__ h2, const float* __restrict__ w3,
    const float* __restrict__ b3, const float* __restrict__ grid_pos,
    const float* __restrict__ tvec, float* __restrict__ grid,
    float* __restrict__ out, const float* __restrict__ head_b)
{
    __shared__ float sh[1088];
    int bx = blockIdx.x;
    int tid = threadIdx.x;
    if (bx < 2048) {
        int b = bx >> 9, k0 = (bx & 511) * 8;
        float (*h2s)[8] = (float (*)[8])sh;
        h2s[tid >> 3][tid & 7] = h2[(((size_t)b * EC + (tid >> 3)) << 12) + k0 + (tid & 7)];
        float w3r[32];
        #pragma unroll
        for (int c4 = 0; c4 < 8; c4++) {
            float4 w4 = *(const float4*)(w3 + tid * 32 + c4 * 4);
            w3r[c4 * 4 + 0] = w4.x; w3r[c4 * 4 + 1] = w4.y;
            w3r[c4 * 4 + 2] = w4.z; w3r[c4 * 4 + 3] = w4.w;
        }
        float base = b3[tid] + tvec[b * D + tid];
        __syncthreads();
        #pragma unroll
        for (int j = 0; j < 8; j++) {
            float s = base + grid_pos[(size_t)(k0 + j) * D + tid];
            #pragma unroll
            for (int ci = 0; ci < 32; ci++) s += h2s[ci][j] * w3r[ci];
            grid[((size_t)b * KK + k0 + j) * D + tid] = s;
        }
    } else {
        out[(bx - 2048) * 256 + tid] = head_b[0];
    }
}

// ================= fused density-inject + layernorm -> bf16 =================
template <int DENS>
__global__ __launch_bounds__(256) void dens_ln_k(
    float* __restrict__ grid, const float* __restrict__ dens,
    const float* __restrict__ dw, const float* __restrict__ db,
    const float* __restrict__ lw, const float* __restrict__ lb,
    unsigned short* __restrict__ y) {
    int row = blockIdx.x * 4 + (threadIdx.x >> 6);
    int lane = threadIdx.x & 63;
    float* gp = grid + (size_t)row * D + lane * 4;
    float4 v = *(float4*)gp;
    if (DENS) {
        float de = dens[row];
        float4 w4 = *(const float4*)(dw + lane * 4);
        float4 b4 = *(const float4*)(db + lane * 4);
        v.x += de * w4.x + b4.x; v.y += de * w4.y + b4.y;
        v.z += de * w4.z + b4.z; v.w += de * w4.w + b4.w;
        *(float4*)gp = v;
    }
    float s = v.x + v.y + v.z + v.w;
    #pragma unroll
    for (int o = 32; o > 0; o >>= 1) s += __shfl_xor(s, o);
    float mean = s * (1.f / D);
    float cx = v.x - mean, cy = v.y - mean, cz = v.z - mean, cw = v.w - mean;
    float q = cx * cx + cy * cy + cz * cz + cw * cw;
    #pragma unroll
    for (int o = 32; o > 0; o >>= 1) q += __shfl_xor(q, o);
    float inv = rsqrtf(q * (1.f / D) + 1e-5f);
    float4 lwv = *(const float4*)(lw + lane * 4);
    float4 lbv = *(const float4*)(lb + lane * 4);
    ushort4 o4;
    o4.x = f2bf(cx * inv * lwv.x + lbv.x);
    o4.y = f2bf(cy * inv * lwv.y + lbv.y);
    o4.z = f2bf(cz * inv * lwv.z + lbv.z);
    o4.w = f2bf(cw * inv * lwv.w + lbv.w);
    *(ushort4*)(y + (size_t)row * D + lane * 4) = o4;
}

// ================= GEMM core (BM=64): C[M,N] = A[M,K] @ Wt[N,K]^T + bias =================
// BM=64, BN=64, BK=64, double-buffered LDS. Used only for the small KV projection now.
// LDS bank-balance swizzle (both-sides-or-neither): staging lane loads global 16B
// column-group (tid&3)^((tid>>3)&3); reads XOR q4 with ((lr>>1)&3).
template <int GELU, int ACCUM, int OBF, int TFPH, int STBF, int KVT = 0>
__device__ __forceinline__ void gemm_core(
    const unsigned short* __restrict__ A, const unsigned short* __restrict__ Wt,
    const float* __restrict__ bias, void* __restrict__ Cv,
    int M, int K, int Nn, int bn, int bm,
    const float* __restrict__ hw, unsigned short* __restrict__ Xb, float scale,
    unsigned short* As, unsigned short* Bs) {
    int tid = threadIdx.x;
    int wave = tid >> 6, lane = tid & 63;
    int q4 = lane >> 4, lr = lane & 15;
    int wn = wave * 16;
    int srow = tid >> 2;
    int sk8 = ((tid & 3) ^ ((tid >> 3) & 3)) * 8;   // swizzled source column-group
    const unsigned short* Ap  = A  + (size_t)(bm + srow) * K + sk8;
    const unsigned short* Bp0 = Wt + (size_t)(bn + srow) * K + sk8;
    unsigned short* AsD = As + tid * 8;
    unsigned short* BsD = Bs + tid * 8;
    int q4x = (q4 ^ ((lr >> 1) & 3)) * 8;           // swizzled read column-group
    f32x4 acc[4] = {};

    gl2lds16(Ap,       AsD);
    gl2lds16(Ap + 32,  AsD + 2048);
    gl2lds16(Bp0,      BsD);
    gl2lds16(Bp0 + 32, BsD + 2048);

    int nk = K >> 6;
    for (int ki = 0; ki < nk; ki++) {
        __syncthreads();
        if (ki + 1 < nk) {
            int k0 = (ki + 1) << 6;
            int nb = ((ki + 1) & 1) * 4096;
            gl2lds16(Ap + k0,       AsD + nb);
            gl2lds16(Ap + k0 + 32,  AsD + nb + 2048);
            gl2lds16(Bp0 + k0,      BsD + nb);
            gl2lds16(Bp0 + k0 + 32, BsD + nb + 2048);
        }
        int cb = (ki & 1) * 4096;
        #pragma unroll
        for (int ks = 0; ks < 2; ks++) {
            bf16x8 af[4], bf;
            #pragma unroll
            for (int i = 0; i < 4; i++)
                af[i] = *(const bf16x8*)&As[cb + ks * 2048 + (i * 16 + lr) * 32 + q4x];
            bf = *(const bf16x8*)&Bs[cb + ks * 2048 + (wn + lr) * 32 + q4x];
            #pragma unroll
            for (int i = 0; i < 4; i++)
                acc[i] = __builtin_amdgcn_mfma_f32_16x16x32_bf16(af[i], bf, acc[i], 0, 0, 0);
        }
    }

    if (KVT) {
        int gc = bn + wn + lr;
        float bv = bias[gc];
        bool isV = gc >= 256;
        #pragma unroll
        for (int i = 0; i < 4; i++) {
            #pragma unroll
            for (int r = 0; r < 4; r++) {
                int gr = bm + i * 16 + q4 * 4 + r;
                if (gr < MSRC) {
                    float v = acc[i][r] + bv;
                    int bb = gr / NS;
                    int tok = gr - bb * NS;
                    if (!isV) {
                        int h = gc >> 5, dh = gc & 31;
                        // permuted K storage: within chunk, token t32 stored at
                        // kk = ((t32&1)<<4) | ((t32>>3)<<2) | ((t32>>1)&3)
                        int t32 = tok & 31;
                        int kkp = ((t32 & 1) << 4) | ((t32 >> 3) << 2) | ((t32 >> 1) & 3);
                        int tokP = (tok & ~31) | kkp;
                        ((unsigned short*)Cv)[(((size_t)(bb * 8 + h) * 544) + tokP) * 32 + dh] = f2bf(v);
                    } else {
                        int gcv = gc - 256;
                        int h = gcv >> 5, dh = gcv & 31;
                        int c = tok >> 5, t32 = tok & 31;
                        Xb[((((size_t)(bb * 8 + h) * 17 + c) * 32 + dh)) * 32 + t32] = f2bf(v);
                    }
                }
            }
        }
        return;
    }

    int gc = bn + wn + lr;
    float bv = bias[gc];
    #pragma unroll
    for (int i = 0; i < 4; i++) {
        #pragma unroll
        for (int r = 0; r < 4; r++) {
            int gr = bm + i * 16 + q4 * 4 + r;
            if (gr < M) {
                float v = (acc[i][r] + bv) * scale;
                if (GELU) v = gelu_f(v);
                size_t idx = (size_t)gr * Nn + gc;
                if (OBF) {
                    ((unsigned short*)Cv)[idx] = f2bf(v);
                } else if (ACCUM) {
                    float nv = ((float*)Cv)[idx] + v;
                    ((float*)Cv)[idx] = nv;
                    if (STBF) Xb[idx] = f2bf(nv);
                } else {
                    ((float*)Cv)[idx] = v;
                }
            }
        }
    }
}

// KV projection: M=2176 (padded), N=512 -> khd (permuted K) + vch (V chunk layout)
__global__ __launch_bounds__(256) void kv_k(
    const unsigned short* __restrict__ srcbf, const unsigned short* __restrict__ kvT,
    const float* __restrict__ kvb, unsigned short* __restrict__ khd,
    unsigned short* __restrict__ vch) {
    __shared__ unsigned short As[8192];
    __shared__ unsigned short Bs[8192];
    gemm_core<0, 0, 1, 0, 0, 1>(srcbf, kvT, kvb, khd, MSRC, D, 512,
                                blockIdx.x * 64, blockIdx.y * 64, nullptr, vch, 1.f, As, Bs);
}

// ================= GEMM BM=128 BK=64: for the grid-limited (512-block) GEMMs =================
// BM=128, BN=64, BK=64, double-buffered LDS (48 KB), same bank swizzle as gemm_core.
// 1D grid + bijective XCD swizzle (nwg % 8 == 0): each XCD owns a contiguous chunk of
// bm-stripes so the A panel shared by the nx bn-blocks of a stripe is fetched by ONE
// XCD's L2 instead of all 8.
template <int GELU, int ACCUM, int OBF, int STBF>
__global__ __launch_bounds__(256) void gemm128_k(
    const unsigned short* __restrict__ A, const unsigned short* __restrict__ Wt,
    const float* __restrict__ bias, void* __restrict__ Cv,
    int M, int K, int Nn, int nx, float scale, unsigned short* __restrict__ Xb) {
    __shared__ unsigned short As[16384];
    __shared__ unsigned short Bs[8192];
    int nwg = gridDim.x;
    int bid = blockIdx.x;
    int wgid = (bid & 7) * (nwg >> 3) + (bid >> 3);   // XCD-chunked remap (bijective)
    int bn = (wgid % nx) * 64;
    int bm = (wgid / nx) * 128;
    int tid = threadIdx.x;
    int wave = tid >> 6, lane = tid & 63;
    int q4 = lane >> 4, lr = lane & 15;
    int wn = wave * 16;
    int srow = tid >> 2;
    int sk8 = ((tid & 3) ^ ((tid >> 3) & 3)) * 8;   // swizzled source column-group
    const unsigned short* Ap  = A + (size_t)(bm + srow) * K + sk8;        // rows 0..63
    const unsigned short* Ap2 = Ap + (size_t)64 * K;                      // rows 64..127
    const unsigned short* Bp  = Wt + (size_t)(bn + srow) * K + sk8;
    unsigned short* AsD = As + tid * 8;
    unsigned short* BsD = Bs + tid * 8;
    int q4x = (q4 ^ ((lr >> 1) & 3)) * 8;           // swizzled read column-group
    f32x4 acc[8] = {};

    gl2lds16(Ap,        AsD);            // rows 0-63,   ks0
    gl2lds16(Ap2,       AsD + 2048);     // rows 64-127, ks0
    gl2lds16(Ap + 32,   AsD + 4096);     // rows 0-63,   ks1
    gl2lds16(Ap2 + 32,  AsD + 6144);     // rows 64-127, ks1
    gl2lds16(Bp,        BsD);
    gl2lds16(Bp + 32,   BsD + 2048);

    int nk = K >> 6;
    for (int ki = 0; ki < nk; ki++) {
        __syncthreads();
        if (ki + 1 < nk) {
            int k0 = (ki + 1) << 6;
            int nbA = ((ki + 1) & 1) * 8192;
            int nbB = ((ki + 1) & 1) * 4096;
            gl2lds16(Ap + k0,        AsD + nbA);
            gl2lds16(Ap2 + k0,       AsD + nbA + 2048);
            gl2lds16(Ap + k0 + 32,   AsD + nbA + 4096);
            gl2lds16(Ap2 + k0 + 32,  AsD + nbA + 6144);
            gl2lds16(Bp + k0,        BsD + nbB);
            gl2lds16(Bp + k0 + 32,   BsD + nbB + 2048);
        }
        int cbA = (ki & 1) * 8192, cbB = (ki & 1) * 4096;
        #pragma unroll
        for (int ks = 0; ks < 2; ks++) {
            bf16x8 bf = *(const bf16x8*)&Bs[cbB + ks * 2048 + (wn + lr) * 32 + q4x];
            #pragma unroll
            for (int i = 0; i < 8; i++) {
                bf16x8 af = *(const bf16x8*)&As[cbA + ks * 4096 + (i * 16 + lr) * 32 + q4x];
                acc[i] = __builtin_amdgcn_mfma_f32_16x16x32_bf16(af, bf, acc[i], 0, 0, 0);
            }
        }
    }

    int gc = bn + wn + lr;
    float bv = bias[gc];
    #pragma unroll
    for (int i = 0; i < 8; i++) {
        #pragma unroll
        for (int r = 0; r < 4; r++) {
            int gr = bm + i * 16 + q4 * 4 + r;
            float v = (acc[i][r] + bv) * scale;
            if (GELU) v = gelu_f(v);
            size_t idx = (size_t)gr * Nn + gc;
            if (OBF) {
                ((unsigned short*)Cv)[idx] = f2bf(v);
            } else if (ACCUM) {
                float nv = ((float*)Cv)[idx] + v;
                ((float*)Cv)[idx] = nv;
                if (STBF) Xb[idx] = f2bf(nv);
            } else {
                ((float*)Cv)[idx] = v;
            }
        }
    }
}

// ================= GEMM BM=128 BK=32: for the LDS-limited ff1 (2048 blocks) ===============
// Half the LDS (24 KB -> 6 blocks/CU vs 3) at half the MFMA-per-barrier; with 6 independent
// blocks/CU the inter-block overlap hides each block's barrier drain (m114 mechanism).
// Same per-chunk LDS layout [rows][32 ush] and identical bank swizzle as gemm128_k.
template <int GELU, int ACCUM, int OBF, int STBF>
__global__ __launch_bounds__(256) void gemm128b32_k(
    const unsigned short* __restrict__ A, const unsigned short* __restrict__ Wt,
    const float* __restrict__ bias, void* __restrict__ Cv,
    int M, int K, int Nn, int nx, float scale, unsigned short* __restrict__ Xb) {
    __shared__ unsigned short As[8192];   // 2 buf x [128 rows][32 ush]
    __shared__ unsigned short Bs[4096];   // 2 buf x [64 rows][32 ush]
    int nwg = gridDim.x;
    int bid = blockIdx.x;
    int wgid = (bid & 7) * (nwg >> 3) + (bid >> 3);   // XCD-chunked remap (bijective)
    int bn = (wgid % nx) * 64;
    int bm = (wgid / nx) * 128;
    int tid = threadIdx.x;
    int wave = tid >> 6, lane = tid & 63;
    int q4 = lane >> 4, lr = lane & 15;
    int wn = wave * 16;
    int srow = tid >> 2;
    int sk8 = ((tid & 3) ^ ((tid >> 3) & 3)) * 8;   // swizzled source column-group (32-wide row)
    const unsigned short* Ap  = A + (size_t)(bm + srow) * K + sk8;        // rows 0..63
    const unsigned short* Ap2 = Ap + (size_t)64 * K;                      // rows 64..127
    const unsigned short* Bp  = Wt + (size_t)(bn + srow) * K + sk8;
    unsigned short* AsD = As + tid * 8;
    unsigned short* BsD = Bs + tid * 8;
    int q4x = (q4 ^ ((lr >> 1) & 3)) * 8;           // swizzled read column-group
    f32x4 acc[8] = {};

    gl2lds16(Ap,   AsD);            // rows 0-63
    gl2lds16(Ap2,  AsD + 2048);     // rows 64-127
    gl2lds16(Bp,   BsD);

    int nk = K >> 5;
    for (int ki = 0; ki < nk; ki++) {
        __syncthreads();
        if (ki + 1 < nk) {
            int k0 = (ki + 1) << 5;
            int nbA = ((ki + 1) & 1) * 4096;
            int nbB = ((ki + 1) & 1) * 2048;
            gl2lds16(Ap + k0,   AsD + nbA);
            gl2lds16(Ap2 + k0,  AsD + nbA + 2048);
            gl2lds16(Bp + k0,   BsD + nbB);
        }
        int cbA = (ki & 1) * 4096, cbB = (ki & 1) * 2048;
        bf16x8 bf = *(const bf16x8*)&Bs[cbB + (wn + lr) * 32 + q4x];
        #pragma unroll
        for (int i = 0; i < 8; i++) {
            bf16x8 af = *(const bf16x8*)&As[cbA + (i * 16 + lr) * 32 + q4x];
            acc[i] = __builtin_amdgcn_mfma_f32_16x16x32_bf16(af, bf, acc[i], 0, 0, 0);
        }
    }

    int gc = bn + wn + lr;
    float bv = bias[gc];
    #pragma unroll
    for (int i = 0; i < 8; i++) {
        #pragma unroll
        for (int r = 0; r < 4; r++) {
            int gr = bm + i * 16 + q4 * 4 + r;
            float v = (acc[i][r] + bv) * scale;
            if (GELU) v = gelu_f(v);
            size_t idx = (size_t)gr * Nn + gc;
            if (OBF) {
                ((unsigned short*)Cv)[idx] = f2bf(v);
            } else if (ACCUM) {
                float nv = ((float*)Cv)[idx] + v;
                ((float*)Cv)[idx] = nv;
                if (STBF) Xb[idx] = f2bf(nv);
            } else {
                ((float*)Cv)[idx] = v;
            }
        }
    }
}

// ================= tfp head GEMM, BM=128: per-task weights + gelu + head-dot epilogue ========
// Same 1D grid + XCD swizzle as gemm128_k (nx = 4).
__global__ __launch_bounds__(256) void tfp128_k(
    const unsigned short* __restrict__ A, const unsigned short* __restrict__ Wt0,
    const float* __restrict__ bias0, float* __restrict__ Cv,
    const int* __restrict__ task_id, const float* __restrict__ hw) {
    __shared__ unsigned short As[16384];
    __shared__ unsigned short Bs[8192];
    int nwg = gridDim.x;
    int bid = blockIdx.x;
    int wgid = (bid & 7) * (nwg >> 3) + (bid >> 3);
    int bn = (wgid & 3) * 64;
    int bm = (wgid >> 2) * 128;
    int tid = threadIdx.x;
    int wave = tid >> 6, lane = tid & 63;
    int q4 = lane >> 4, lr = lane & 15;
    int wn = wave * 16;
    int t = task_id[bm >> 12];
    const unsigned short* Wt = Wt0 + (size_t)t * D * D;
    const float* bias = bias0 + t * D;
    int srow = tid >> 2;
    int sk8 = ((tid & 3) ^ ((tid >> 3) & 3)) * 8;
    const unsigned short* Ap  = A + (size_t)(bm + srow) * D + sk8;
    const unsigned short* Ap2 = Ap + (size_t)64 * D;
    const unsigned short* Bp  = Wt + (size_t)(bn + srow) * D + sk8;
    unsigned short* AsD = As + tid * 8;
    unsigned short* BsD = Bs + tid * 8;
    int q4x = (q4 ^ ((lr >> 1) & 3)) * 8;
    f32x4 acc[8] = {};

    gl2lds16(Ap,        AsD);
    gl2lds16(Ap2,       AsD + 2048);
    gl2lds16(Ap + 32,   AsD + 4096);
    gl2lds16(Ap2 + 32,  AsD + 6144);
    gl2lds16(Bp,        BsD);
    gl2lds16(Bp + 32,   BsD + 2048);

    int nk = D >> 6;
    for (int ki = 0; ki < nk; ki++) {
        __syncthreads();
        if (ki + 1 < nk) {
            int k0 = (ki + 1) << 6;
            int nbA = ((ki + 1) & 1) * 8192;
            int nbB = ((ki + 1) & 1) * 4096;
            gl2lds16(Ap + k0,        AsD + nbA);
            gl2lds16(Ap2 + k0,       AsD + nbA + 2048);
            gl2lds16(Ap + k0 + 32,   AsD + nbA + 4096);
            gl2lds16(Ap2 + k0 + 32,  AsD + nbA + 6144);
            gl2lds16(Bp + k0,        BsD + nbB);
            gl2lds16(Bp + k0 + 32,   BsD + nbB + 2048);
        }
        int cbA = (ki & 1) * 8192, cbB = (ki & 1) * 4096;
        #pragma unroll
        for (int ks = 0; ks < 2; ks++) {
            bf16x8 bf = *(const bf16x8*)&Bs[cbB + ks * 2048 + (wn + lr) * 32 + q4x];
            #pragma unroll
            for (int i = 0; i < 8; i++) {
                bf16x8 af = *(const bf16x8*)&As[cbA + ks * 4096 + (i * 16 + lr) * 32 + q4x];
                acc[i] = __builtin_amdgcn_mfma_f32_16x16x32_bf16(af, bf, acc[i], 0, 0, 0);
            }
        }
    }

    int gc = bn + wn + lr;
    float bv = bias[gc];
    float hv = hw[gc];
    #pragma unroll
    for (int i = 0; i < 8; i++) {
        #pragma unroll
        for (int r = 0; r < 4; r++) {
            float s = gelu_f(acc[i][r] + bv) * hv;
            s += __shfl_xor(s, 1); s += __shfl_xor(s, 2);
            s += __shfl_xor(s, 4); s += __shfl_xor(s, 8);
            if (lr == 0)
                atomicAdd(Cv + (bm + i * 16 + q4 * 4 + r), s);
        }
    }
}

// ================= MFMA flash cross-attention: qt-PAIR per block, shared K/V =========
// S' = K Q^T (query=col, q pre-scaled isq*log2e), p = exp2(s - dist'); O^T = V^T P'.
// K chunk rows are permuted so the S' C/D layout IS the PV B-operand layout (no cross-lane).
// One block = (b, h, qt-pair): rows qt0=2*qp and qt1=qt0+1 SHARE the K/V fragments
// (K/V L2 traffic per query halves vs per-qt blocks) and share dx^2 in DIST; two
// independent QK->exp2->PV chains per wave double ILP to offset the TLP drop.
// 2-deep register prefetch, stages X/Y.
__global__ __launch_bounds__(256) void attn_mfma(
    const unsigned short* __restrict__ qb,
    const unsigned short* __restrict__ khd,
    const unsigned short* __restrict__ vch,
    const float* __restrict__ sxy,
    unsigned short* __restrict__ out)
{
    __shared__ float2 sxys[NSP];
    int bid = blockIdx.x;                    // b*256 + h*32 + qp
    int qp = bid & 31, h = (bid >> 5) & 7, b = bid >> 8;
    int qt0 = qp * 2;
    int tid = threadIdx.x, wave = tid >> 6, lane = tid & 63;
    int q4 = lane >> 4, lr = lane & 15;

    int cell0 = qt0 * 64 + wave * 16 + lr;           // query grid cell, row qt0
    size_t qrow0 = (size_t)(b * KK + cell0);
    size_t qrow1 = qrow0 + 64;                       // row qt0+1, same x
    bf16x8 qfA = *(const bf16x8*)(qb + qrow0 * D + h * DH + q4 * 8);
    bf16x8 qfB = *(const bf16x8*)(qb + qrow1 * D + h * DH + q4 * 8);
    const unsigned short* kp0 = khd + ((size_t)(b * 8 + h) * 544) * 32 + lr * 32 + q4 * 8;
    const unsigned short* vb0 = vch + ((size_t)(b * 8 + h) * 17) * 1024 + lr * 32 + q4 * 8;

    float lla0 = 0.f, lla1 = 0.f, llb0 = 0.f, llb1 = 0.f;
    f32x4 o0a = {0.f, 0.f, 0.f, 0.f}, o1a = {0.f, 0.f, 0.f, 0.f};
    f32x4 o0b = {0.f, 0.f, 0.f, 0.f}, o1b = {0.f, 0.f, 0.f, 0.f};

    bf16x8 k0X, k1X, v0X, v1X, k0Y, k1Y, v0Y, v1Y;
    f32x4 d0X, d1X, d0Y, d1Y;    // dist*log2e, row qt0 (slots: d0 = even tokens, d1 = odd)
    f32x4 e0X, e1X, e0Y, e1Y;    // dist*log2e, row qt1

#define LDK(S, c) { size_t co = (size_t)(c) * 1024; \
    k0##S = *(const bf16x8*)(kp0 + co); k1##S = *(const bf16x8*)(kp0 + co + 512); }
#define LDV(S, c) { size_t co = (size_t)(c) * 1024; \
    v0##S = *(const bf16x8*)(vb0 + co); v1##S = *(const bf16x8*)(vb0 + co + 512); }

    // issue global K/V prefetch before LDS staging so HBM latency overlaps it
    LDK(X, 0); LDV(X, 0);
    LDK(Y, 1); LDV(Y, 1);

    // stage (x*log2e, y*log2e); pads -> huge dist -> p = 0
    const float2* sb = (const float2*)(sxy + 2 * (size_t)b * NS);
    for (int i = tid; i < NSP; i += 256) {
        float2 v = (i < NS) ? sb[i] : make_float2(1.e4f, 1.e4f);
        sxys[i] = make_float2(v.x * LOG2E, v.y * LOG2E);
    }
    __syncthreads();

    int qi = wave * 16 + lr;                         // query x-cell (shared by both rows)
    float gxp  = (qi + 0.5f) * (1.f / 64.f) * LOG2E;
    float gy0p = (qt0 + 0.5f) * (1.f / 64.f) * LOG2E;
    float gy1p = (qt0 + 1.5f) * (1.f / 64.f) * LOG2E;
    const float2* spf = &sxys[q4 * 8];

    // dist for both rows; dx^2 shared (same query x)
#define DIST2(xx, yy, dq0, dq1) { float dx_ = gxp - (xx); float dx2_ = dx_ * dx_; \
    float dy0_ = gy0p - (yy); dq0 = __builtin_amdgcn_sqrtf(__builtin_fmaf(dy0_, dy0_, dx2_)); \
    float dy1_ = gy1p - (yy); dq1 = __builtin_amdgcn_sqrtf(__builtin_fmaf(dy1_, dy1_, dx2_)); }
    // tokens for this lane in chunk c: c*32 + q4*8 + {0..7}; slot r of s0 uses token 2r,
    // slot r of s1 uses token 2r+1 (the K permutation).
#define LDB(S, c) { const float4* p4_ = (const float4*)(spf + (size_t)(c) * 32); \
    float4 a0_ = p4_[0], a1_ = p4_[1], a2_ = p4_[2], a3_ = p4_[3]; \
    DIST2(a0_.x, a0_.y, d0##S[0], e0##S[0]); DIST2(a0_.z, a0_.w, d1##S[0], e1##S[0]); \
    DIST2(a1_.x, a1_.y, d0##S[1], e0##S[1]); DIST2(a1_.z, a1_.w, d1##S[1], e1##S[1]); \
    DIST2(a2_.x, a2_.y, d0##S[2], e0##S[2]); DIST2(a2_.z, a2_.w, d1##S[2], e1##S[2]); \
    DIST2(a3_.x, a3_.y, d0##S[3], e0##S[3]); DIST2(a3_.z, a3_.w, d1##S[3], e1##S[3]); }

    LDB(X, 0); LDB(Y, 1);

#define BODY(S, cp) { \
    f32x4 s0a = {0.f, 0.f, 0.f, 0.f}, s1a = {0.f, 0.f, 0.f, 0.f}; \
    f32x4 s0b = {0.f, 0.f, 0.f, 0.f}, s1b = {0.f, 0.f, 0.f, 0.f}; \
    s0a = __builtin_amdgcn_mfma_f32_16x16x32_bf16(k0##S, qfA, s0a, 0, 0, 0); \
    s1a = __builtin_amdgcn_mfma_f32_16x16x32_bf16(k1##S, qfA, s1a, 0, 0, 0); \
    s0b = __builtin_amdgcn_mfma_f32_16x16x32_bf16(k0##S, qfB, s0b, 0, 0, 0); \
    s1b = __builtin_amdgcn_mfma_f32_16x16x32_bf16(k1##S, qfB, s1b, 0, 0, 0); \
    LDK(S, cp); \
    float p0a[4], p1a[4], p0b[4], p1b[4]; \
    p0a[0] = __builtin_amdgcn_exp2f(s0a[0] - d0##S[0]); \
    p0a[1] = __builtin_amdgcn_exp2f(s0a[1] - d0##S[1]); \
    p0a[2] = __builtin_amdgcn_exp2f(s0a[2] - d0##S[2]); \
    p0a[3] = __builtin_amdgcn_exp2f(s0a[3] - d0##S[3]); \
    p1a[0] = __builtin_amdgcn_exp2f(s1a[0] - d1##S[0]); \
    p1a[1] = __builtin_amdgcn_exp2f(s1a[1] - d1##S[1]); \
    p1a[2] = __builtin_amdgcn_exp2f(s1a[2] - d1##S[2]); \
    p1a[3] = __builtin_amdgcn_exp2f(s1a[3] - d1##S[3]); \
    p0b[0] = __builtin_amdgcn_exp2f(s0b[0] - e0##S[0]); \
    p0b[1] = __builtin_amdgcn_exp2f(s0b[1] - e0##S[1]); \
    p0b[2] = __builtin_amdgcn_exp2f(s0b[2] - e0##S[2]); \
    p0b[3] = __builtin_amdgcn_exp2f(s0b[3] - e0##S[3]); \
    p1b[0] = __builtin_amdgcn_exp2f(s1b[0] - e1##S[0]); \
    p1b[1] = __builtin_amdgcn_exp2f(s1b[1] - e1##S[1]); \
    p1b[2] = __builtin_amdgcn_exp2f(s1b[2] - e1##S[2]); \
    p1b[3] = __builtin_amdgcn_exp2f(s1b[3] - e1##S[3]); \
    LDB(S, cp); \
    lla0 += (p0a[0] + p0a[1]) + (p0a[2] + p0a[3]); \
    lla1 += (p1a[0] + p1a[1]) + (p1a[2] + p1a[3]); \
    llb0 += (p0b[0] + p0b[1]) + (p0b[2] + p0b[3]); \
    llb1 += (p1b[0] + p1b[1]) + (p1b[2] + p1b[3]); \
    union { unsigned u[4]; bf16x8 v; } pua, pub; \
    pua.u[0] = cvtpk(p0a[0], p1a[0]); \
    pua.u[1] = cvtpk(p0a[1], p1a[1]); \
    pua.u[2] = cvtpk(p0a[2], p1a[2]); \
    pua.u[3] = cvtpk(p0a[3], p1a[3]); \
    pub.u[0] = cvtpk(p0b[0], p1b[0]); \
    pub.u[1] = cvtpk(p0b[1], p1b[1]); \
    pub.u[2] = cvtpk(p0b[2], p1b[2]); \
    pub.u[3] = cvtpk(p0b[3], p1b[3]); \
    o0a = __builtin_amdgcn_mfma_f32_16x16x32_bf16(v0##S, pua.v, o0a, 0, 0, 0); \
    o1a = __builtin_amdgcn_mfma_f32_16x16x32_bf16(v1##S, pua.v, o1a, 0, 0, 0); \
    o0b = __builtin_amdgcn_mfma_f32_16x16x32_bf16(v0##S, pub.v, o0b, 0, 0, 0); \
    o1b = __builtin_amdgcn_mfma_f32_16x16x32_bf16(v1##S, pub.v, o1b, 0, 0, 0); \
    LDV(S, cp); \
}

    for (int c = 0; c < 16; c += 2) {
        int cpX = c + 2;                       // c <= 14 -> cpX <= 16, always valid
        int cpY = (c + 3 > 16) ? 16 : c + 3;   // clamp; redundant reload is harmless
        BODY(X, cpX);
        BODY(Y, cpY);
    }
    BODY(X, 16);   // chunk 16 tail; trailing prefetch is dead and DCE'd

#undef BODY
#undef LDB
#undef DIST2
#undef LDK
#undef LDV

    float lla = lla0 + lla1;
    lla += __shfl_xor(lla, 16);
    lla += __shfl_xor(lla, 32);
    float inva = 1.f / lla;
    float llb = llb0 + llb1;
    llb += __shfl_xor(llb, 16);
    llb += __shfl_xor(llb, 32);
    float invb = 1.f / llb;
    uint2 sa0, sa1, sb0, sb1;
    sa0.x = cvtpk(o0a[0] * inva, o0a[1] * inva);
    sa0.y = cvtpk(o0a[2] * inva, o0a[3] * inva);
    sa1.x = cvtpk(o1a[0] * inva, o1a[1] * inva);
    sa1.y = cvtpk(o1a[2] * inva, o1a[3] * inva);
    sb0.x = cvtpk(o0b[0] * invb, o0b[1] * invb);
    sb0.y = cvtpk(o0b[2] * invb, o0b[3] * invb);
    sb1.x = cvtpk(o1b[0] * invb, o1b[1] * invb);
    sb1.y = cvtpk(o1b[2] * invb, o1b[3] * invb);
    *(uint2*)(out + qrow0 * D + h * DH + q4 * 4) = sa0;
    *(uint2*)(out + qrow0 * D + h * DH + 16 + q4 * 4) = sa1;
    *(uint2*)(out + qrow1 * D + h * DH + q4 * 4) = sb0;
    *(uint2*)(out + qrow1 * D + h * DH + 16 + q4 * 4) = sb1;
}

extern "C" void kernel_launch(void* const* d_in, const int* in_sizes, int n_in,
                              void* d_out, int out_size, void* d_ws, size_t ws_size,
                              hipStream_t stream) {
    const float* meas_xy = (const float*)d_in[0];
    const float* meas_v  = (const float*)d_in[1];
    const float* bs_xy   = (const float*)d_in[2];
    const int*   task_id = (const int*)d_in[3];
    const float* city    = (const float*)d_in[4];
    const float* mp_w1 = (const float*)d_in[5];  const float* mp_b1 = (const float*)d_in[6];
    const float* mp_w2 = (const float*)d_in[7];  const float* mp_b2 = (const float*)d_in[8];
    const float* bp_w1 = (const float*)d_in[9];  const float* bp_b1 = (const float*)d_in[10];
    const float* bp_w2 = (const float*)d_in[11]; const float* bp_b2 = (const float*)d_in[12];
    const float* env_w1 = (const float*)d_in[13]; const float* env_b1 = (const float*)d_in[14];
    const float* env_w2 = (const float*)d_in[15]; const float* env_b2 = (const float*)d_in[16];
    const float* env_w3 = (const float*)d_in[17]; const float* env_b3 = (const float*)d_in[18];
    const float* task_emb = (const float*)d_in[19];
    const float* tp_w = (const float*)d_in[20]; const float* tp_b = (const float*)d_in[21];
    const float* grid_pos = (const float*)d_in[22];
    const float* dens_w = (const float*)d_in[23]; const float* dens_b = (const float*)d_in[24];
    const float* ln1_w = (const float*)d_in[25]; const float* ln1_b = (const float*)d_in[26];
    const float* wq = (const float*)d_in[27]; const float* bq = (const float*)d_in[28];
    const float* wk = (const float*)d_in[29]; const float* bk = (const float*)d_in[30];
    const float* wv = (const float*)d_in[31]; const float* bv = (const float*)d_in[32];
    const float* wo = (const float*)d_in[33]; const float* bo = (const float*)d_in[34];
    const float* ln2_w = (const float*)d_in[35]; const float* ln2_b = (const float*)d_in[36];
    const float* ff_w1 = (const float*)d_in[37]; const float* ff_b1 = (const float*)d_in[38];
    const float* ff_w2 = (const float*)d_in[39]; const float* ff_b2 = (const float*)d_in[40];
    const float* tfp_w = (const float*)d_in[41]; const float* tfp_b = (const float*)d_in[42];
    const float* head_w = (const float*)d_in[43]; const float* head_b = (const float*)d_in[44];
    float* out = (float*)d_out;

    float* ws = (float*)d_ws;
    size_t off = 0;
    float* src_xy = ws + off; off += (size_t)B * NS * 2 + 128;
    float* dens   = ws + off; off += (size_t)B * KK;
    float* tvec   = ws + off; off += (size_t)B * D;
    float* h1     = ws + off; off += (size_t)B * EC * KK;
    float* grid   = ws + off; off += (size_t)B * KK * D;
    unsigned short* srcbf = (unsigned short*)(ws + off); off += (size_t)MSRCP * D / 2;
    unsigned short* khd   = (unsigned short*)(ws + off); off += (size_t)B * 8 * 544 * 32 / 2;
    unsigned short* vch   = (unsigned short*)(ws + off); off += (size_t)B * 8 * 17 * 1024 / 2;
    float* qreg   = ws + off; off += (size_t)B * KK * D / 2;   // qbf; hosts h2 f32 early
    unsigned short* qbf = (unsigned short*)qreg;
    float* h2     = qreg;
    unsigned short* xbf    = (unsigned short*)(ws + off); off += (size_t)B * KK * D / 2;
    unsigned short* attnbf = (unsigned short*)(ws + off); off += (size_t)B * KK * D / 2;
    unsigned short* hidbf  = (unsigned short*)(ws + off); off += (size_t)B * KK * DFF / 2;    // 32 MB
    unsigned short* wqT  = (unsigned short*)(ws + off); off += (size_t)LYR * D * D / 2;
    unsigned short* kvT  = (unsigned short*)(ws + off); off += (size_t)LYR * 512 * D / 2;
    unsigned short* woT  = (unsigned short*)(ws + off); off += (size_t)LYR * D * D / 2;
    unsigned short* ff1T = (unsigned short*)(ws + off); off += (size_t)LYR * D * DFF / 2;
    unsigned short* ff2T = (unsigned short*)(ws + off); off += (size_t)LYR * DFF * D / 2;
    unsigned short* tfpT = (unsigned short*)(ws + off); off += (size_t)T * D * D / 2;
    float* kvbias = ws + off; off += (size_t)LYR * 512;
    (void)ws_size; (void)n_in; (void)in_sizes; (void)out_size;

    const int M = B * KK;       // 16384

    pre1_k<<<6116, 256, 0, stream>>>(
        wq, wk, wv, wo, ff_w1, ff_w2, tfp_w, bk, bv,
        wqT, kvT, woT, ff1T, ff2T, tfpT, kvbias,
        meas_xy, meas_v, bs_xy, mp_w1, mp_b1, mp_w2, mp_b2,
        bp_w1, bp_b1, bp_w2, bp_b2, srcbf, src_xy,
        dens, city, env_w1, env_b1, h1,
        task_emb, task_id, tp_w, tp_b, tvec, khd, vch);
    conv2_k<<<512, 256, 0, stream>>>(h1, env_w2, env_b2, h2);
    pre2_k<<<2112, 256, 0, stream>>>(h2, env_w3, env_b3, grid_pos, tvec, grid,
                                     out, head_b);

    for (int l = 0; l < LYR; l++) {
        dens_ln_k<1><<<M / 4, 256, 0, stream>>>(grid, dens, dens_w + l * D, dens_b + l * D,
                                                ln1_w + l * D, ln1_b + l * D, xbf);
        gemm128_k<0, 0, 1, 0><<<512, 256, 0, stream>>>(
            xbf, wqT + (size_t)l * D * D, bq + l * D, qbf, M, D, D, 4, ISQ * LOG2E, nullptr);
        kv_k<<<dim3(8, 34), 256, 0, stream>>>(
            srcbf, kvT + (size_t)l * 512 * D, kvbias + l * 512, khd, vch);
        attn_mfma<<<B * NH * 32, 256, 0, stream>>>(qbf, khd, vch, src_xy, attnbf);
        gemm128_k<0, 1, 0, 0><<<512, 256, 0, stream>>>(
            attnbf, woT + (size_t)l * D * D, bo + l * D, grid, M, D, D, 4, 1.f, nullptr);
        dens_ln_k<0><<<M / 4, 256, 0, stream>>>(grid, nullptr, nullptr, nullptr,
                                                ln2_w + l * D, ln2_b + l * D, xbf);
        gemm128b32_k<1, 0, 1, 0><<<2048, 256, 0, stream>>>(
            xbf, ff1T + (size_t)l * D * DFF, ff_b1 + l * DFF, hidbf, M, D, DFF, 16, 1.f, nullptr);
        if (l == 0) {
            gemm128_k<0, 1, 0, 0><<<512, 256, 0, stream>>>(
                hidbf, ff2T + (size_t)l * DFF * D, ff_b2 + l * D, grid, M, DFF, D, 4, 1.f, nullptr);
        } else {
            gemm128_k<0, 1, 0, 1><<<512, 256, 0, stream>>>(
                hidbf, ff2T + (size_t)l * DFF * D, ff_b2 + l * D, grid, M, DFF, D, 4, 1.f, xbf);
        }
    }
    tfp128_k<<<512, 256, 0, stream>>>(xbf, tfpT, tfp_b, out, task_id, head_w);
}

// Round 11
// 479.924 us; speedup vs baseline: 1.0143x; 1.0143x over previous
//
#include <hip/hip_runtime.h>
#include <hip/hip_bf16.h>
#include <math.h>

#define D 256
#define NH 8
#define DH 32
#define LYR 2
#define G 64
#define KK 4096
#define T 4
#define EC 32
#define B 4
#define N 512
#define CITY 256
#define DFF 1024
#define NS 513    // N + 1 bs token
#define NSP 544   // 17 * 32 padded token count
#define MSRC 2052 // B * NS
#define MSRCP 2176 // padded to 34*64
#define ISQ 0.17677669529663687f
#define LOG2E 1.4426950408889634f

typedef short bf16x8 __attribute__((ext_vector_type(8)));
typedef float f32x4 __attribute__((ext_vector_type(4)));

// gelu via exact identity 0.5*(1+tanh(u)) == sigmoid(2u); exp2+rcp, ~7 VALU vs libm tanhf
__device__ __forceinline__ float gelu_f(float x) {
    const float c2 = 2.f * 0.7978845608028654f * LOG2E;  // 2*c*log2e
    float u = x + 0.044715f * x * x * x;
    float e = __builtin_amdgcn_exp2f(-c2 * u);
    return x * __builtin_amdgcn_rcpf(1.f + e);
}

__device__ __forceinline__ unsigned short f2bf(float f) {
    unsigned int u = __float_as_uint(f);
    unsigned int r = (u + 0x7FFFu + ((u >> 16) & 1u)) >> 16;
    return (unsigned short)r;
}

__device__ __forceinline__ float bf2f(unsigned short u) {
    return __uint_as_float((unsigned)u << 16);
}

__device__ __forceinline__ unsigned cvtpk(float a, float b) {
    unsigned r;
    asm("v_cvt_pk_bf16_f32 %0, %1, %2" : "=v"(r) : "v"(a), "v"(b));
    return r;
}

__device__ __forceinline__ void gl2lds16(const unsigned short* g, unsigned short* l) {
    __builtin_amdgcn_global_load_lds(
        (const __attribute__((address_space(1))) unsigned int*)g,
        (__attribute__((address_space(3))) unsigned int*)l, 16, 0, 0);
}

// ================= pre1: transposes + tok_mlp + density + conv1 + tvec + K/V pad zero ===========
__global__ __launch_bounds__(256) void pre1_k(
    const float* __restrict__ wq, const float* __restrict__ wk,
    const float* __restrict__ wv, const float* __restrict__ wo,
    const float* __restrict__ ff1, const float* __restrict__ ff2,
    const float* __restrict__ tfp,
    const float* __restrict__ bk, const float* __restrict__ bv,
    unsigned short* __restrict__ wqT, unsigned short* __restrict__ kvT,
    unsigned short* __restrict__ woT, unsigned short* __restrict__ ff1T,
    unsigned short* __restrict__ ff2T, unsigned short* __restrict__ tfpT,
    float* __restrict__ kvbias,
    const float* __restrict__ meas_xy, const float* __restrict__ meas_v,
    const float* __restrict__ bs_xy,
    const float* __restrict__ mp_w1, const float* __restrict__ mp_b1,
    const float* __restrict__ mp_w2, const float* __restrict__ mp_b2,
    const float* __restrict__ bp_w1, const float* __restrict__ bp_b1,
    const float* __restrict__ bp_w2, const float* __restrict__ bp_b2,
    unsigned short* __restrict__ srcbf, float* __restrict__ src_xy,
    float* __restrict__ dens,
    const float* __restrict__ city, const float* __restrict__ env_w1,
    const float* __restrict__ env_b1, float* __restrict__ h1,
    const float* __restrict__ task_emb, const int* __restrict__ task_id,
    const float* __restrict__ tp_w, const float* __restrict__ tp_b,
    float* __restrict__ tvec,
    unsigned short* __restrict__ khd, unsigned short* __restrict__ vch)
{
    __shared__ float sh[1088];
    int bx = blockIdx.x;
    int tid = threadIdx.x;
    if (bx < 1792) {
        const float* src; unsigned short* dst;
        int Kd, Nn, nmat, rowOff = 0, t; size_t matStride;
        if (bx < 512) {
            int job = bx >> 7; t = bx & 127;
            Kd = 256; Nn = 256; nmat = 2;
            if (job == 0)      { src = wq; dst = wqT; matStride = 65536; }
            else if (job == 1) { src = wk; dst = kvT; matStride = 131072; }
            else if (job == 2) { src = wv; dst = kvT; matStride = 131072; rowOff = 256; }
            else               { src = wo; dst = woT; matStride = 65536; }
            if ((t & 63) == 0 && job == 1) kvbias[(t >> 6) * 512 + tid] = bk[(t >> 6) * 256 + tid];
            if ((t & 63) == 0 && job == 2) kvbias[(t >> 6) * 512 + 256 + tid] = bv[(t >> 6) * 256 + tid];
        } else if (bx < 1024) { t = bx - 512;  src = ff1; dst = ff1T; Kd = 256;  Nn = 1024; nmat = 2; matStride = 262144; }
        else if (bx < 1536)   { t = bx - 1024; src = ff2; dst = ff2T; Kd = 1024; Nn = 256;  nmat = 2; matStride = 262144; }
        else                  { t = bx - 1536; src = tfp; dst = tfpT; Kd = 256;  Nn = 256;  nmat = 4; matStride = 65536; }
        int tn = Nn / 32, perMat = tn * (Kd / 32);
        int mat = t / perMat;
        int rem = t - mat * perMat;
        int nb = (rem % tn) * 32, kb = (rem / tn) * 32;
        const float* s = src + (size_t)mat * Kd * Nn;
        unsigned short* d = dst + (size_t)mat * matStride;
        float (*tb)[33] = (float (*)[33])sh;
        int tx = tid & 31, ty = tid >> 5;
        #pragma unroll
        for (int i = 0; i < 4; i++)
            tb[ty + i * 8][tx] = s[(size_t)(kb + ty + i * 8) * Nn + nb + tx];
        __syncthreads();
        #pragma unroll
        for (int i = 0; i < 4; i++)
            d[(size_t)(rowOff + nb + ty + i * 8) * Kd + kb + tx] = f2bf(tb[tx][ty + i * 8]);
    } else if (bx < 3968) {
        int id = bx - 1792;
        int dd = tid;
        if (id >= B * N + B) {
            srcbf[(size_t)id * D + dd] = 0;
            return;
        }
        float* hid = sh;
        int row;
        const float *w1, *b1, *w2, *b2;
        float x0, x1, x2 = 0.f;
        int nin;
        if (id < B * N) {
            int b = id >> 9, n = id & 511;
            x0 = meas_xy[(b * N + n) * 2 + 0];
            x1 = meas_xy[(b * N + n) * 2 + 1];
            x2 = meas_v[b * N + n];
            w1 = mp_w1; b1 = mp_b1; w2 = mp_w2; b2 = mp_b2; nin = 3;
            row = b * NS + n;
        } else {
            int b = id - B * N;
            x0 = bs_xy[b * 2 + 0];
            x1 = bs_xy[b * 2 + 1];
            w1 = bp_w1; b1 = bp_b1; w2 = bp_w2; b2 = bp_b2; nin = 2;
            row = b * NS + N;
        }
        float h = x0 * w1[dd] + x1 * w1[D + dd] + b1[dd];
        if (nin == 3) h += x2 * w1[2 * D + dd];
        hid[dd] = gelu_f(h);
        __syncthreads();
        float o = b2[dd];
        for (int j = 0; j < D; j++) o += hid[j] * w2[j * D + dd];
        srcbf[(size_t)row * D + dd] = f2bf(o);
        if (dd == 0) { src_xy[row * 2 + 0] = x0; src_xy[row * 2 + 1] = x1; }
    } else if (bx < 4032) {
        int blk = bx - 3968;
        int b = blk >> 4, kc = blk & 15;
        int k = kc * 256 + tid;
        float* mx = sh; float* my = sh + 512;
        for (int i = tid; i < N; i += 256) {
            mx[i] = meas_xy[(b * N + i) * 2 + 0];
            my[i] = meas_xy[(b * N + i) * 2 + 1];
        }
        __syncthreads();
        float gx = ((k & 63) + 0.5f) / 64.f;
        float gy = ((k >> 6) + 0.5f) / 64.f;
        float s = 0.f;
        for (int n = 0; n < N; n++) {
            float dx = gx - mx[n], dy = gy - my[n];
            s += __expf(-(dx * dx + dy * dy) * 78.125f);
        }
        dens[b * KK + k] = s * (1.f / (float)N);
    } else if (bx < 6080) {
        int i = (bx - 4032) * 256 + tid;
        int x = i & 63, y = (i >> 6) & 63, c = (i >> 12) & 31, b = i >> 17;
        float s = env_b1[c];
        for (int ky = 0; ky < 3; ky++) {
            int yy = y + ky - 1;
            if (yy < 0 || yy >= G) continue;
            for (int kx = 0; kx < 3; kx++) {
                int xx = x + kx - 1;
                if (xx < 0 || xx >= G) continue;
                s += city[(b * CITY + yy * 4) * CITY + xx * 4] * env_w1[c * 9 + ky * 3 + kx];
            }
        }
        h1[i] = gelu_f(s);
    } else if (bx < 6084) {
        int b = bx - 6080;
        float* e = sh;
        e[tid] = task_emb[task_id[b] * D + tid];
        __syncthreads();
        float s = tp_b[tid];
        for (int j = 0; j < D; j++) s += e[j] * tp_w[j * D + tid];
        tvec[b * D + tid] = s;
    } else {
        int bh = bx - 6084;     // 0..31
        unsigned short* kp = khd + ((size_t)bh * 544 + 513) * 32;
        for (int i = tid; i < 992; i += 256) kp[i] = 0;
        unsigned short* vp = vch + ((size_t)bh * 17 + 16) * 1024;
        for (int i = tid; i < 1024; i += 256) vp[i] = 0;
    }
}

// ================= conv2: branchless, 4 c_out/thread, ci-pipelined =================
__global__ __launch_bounds__(256) void conv2_k(
    const float* __restrict__ h1, const float* __restrict__ w,
    const float* __restrict__ bias, float* __restrict__ h2) {
    int blk = blockIdx.x;
    int yt = blk & 15, cg = (blk >> 4) & 7, b = blk >> 7;
    int x = threadIdx.x & 63, y = yt * 4 + (threadIdx.x >> 6);
    int c0 = cg * 4;
    float flag[9];
    int off[9];
    #pragma unroll
    for (int ky = 0; ky < 3; ky++) {
        int yy = y + ky - 1;
        bool vy = (yy >= 0 && yy < G);
        int yc = min(max(yy, 0), G - 1);
        #pragma unroll
        for (int kx = 0; kx < 3; kx++) {
            int xx = x + kx - 1;
            bool vx = (xx >= 0 && xx < G);
            int xc = min(max(xx, 0), G - 1);
            flag[ky * 3 + kx] = (vy && vx) ? 1.f : 0.f;
            off[ky * 3 + kx] = yc * G + xc;
        }
    }
    const float* hp = h1 + ((size_t)(b * EC) << 12);
    float acc[4] = {bias[c0], bias[c0 + 1], bias[c0 + 2], bias[c0 + 3]};
    float v[9], nv[9];
    #pragma unroll
    for (int t = 0; t < 9; t++) v[t] = hp[off[t]] * flag[t];
    for (int ci = 0; ci < EC; ci++) {
        if (ci < EC - 1) {
            const float* hn = hp + ((size_t)(ci + 1) << 12);
            #pragma unroll
            for (int t = 0; t < 9; t++) nv[t] = hn[off[t]] * flag[t];
        }
        #pragma unroll
        for (int cc = 0; cc < 4; cc++) {
            const float* wp = w + ((size_t)(c0 + cc) * EC + ci) * 9;
            #pragma unroll
            for (int t = 0; t < 9; t++) acc[cc] += v[t] * wp[t];
        }
        #pragma unroll
        for (int t = 0; t < 9; t++) v[t] = nv[t];
    }
    size_t obase = (((size_t)(b * EC + c0)) << 12) + y * G + x;
    #pragma unroll
    for (int cc = 0; cc < 4; cc++)
        h2[obase + ((size_t)cc << 12)] = gelu_f(acc[cc]);
}

// ================= pre2: grid_init + out_init (nd bias computed in attn) =================
__global__ __launch_bounds__(256) void pre2_k(
    const float* __restrict__ h2, const float* __restrict__ w3,
    const float* __restrict__ b3, const float* __restrict__ grid_pos,
    const float* __restrict__ tvec, float* __restrict__ grid,
    float* __restrict__ out, const float* __restrict__ head_b)
{
    __shared__ float sh[1088];
    int bx = blockIdx.x;
    int tid = threadIdx.x;
    if (bx < 2048) {
        int b = bx >> 9, k0 = (bx & 511) * 8;
        float (*h2s)[8] = (float (*)[8])sh;
        h2s[tid >> 3][tid & 7] = h2[(((size_t)b * EC + (tid >> 3)) << 12) + k0 + (tid & 7)];
        float w3r[32];
        #pragma unroll
        for (int c4 = 0; c4 < 8; c4++) {
            float4 w4 = *(const float4*)(w3 + tid * 32 + c4 * 4);
            w3r[c4 * 4 + 0] = w4.x; w3r[c4 * 4 + 1] = w4.y;
            w3r[c4 * 4 + 2] = w4.z; w3r[c4 * 4 + 3] = w4.w;
        }
        float base = b3[tid] + tvec[b * D + tid];
        __syncthreads();
        #pragma unroll
        for (int j = 0; j < 8; j++) {
            float s = base + grid_pos[(size_t)(k0 + j) * D + tid];
            #pragma unroll
            for (int ci = 0; ci < 32; ci++) s += h2s[ci][j] * w3r[ci];
            grid[((size_t)b * KK + k0 + j) * D + tid] = s;
        }
    } else {
        out[(bx - 2048) * 256 + tid] = head_b[0];
    }
}

// ================= fused density-inject + layernorm -> bf16 =================
template <int DENS>
__global__ __launch_bounds__(256) void dens_ln_k(
    float* __restrict__ grid, const float* __restrict__ dens,
    const float* __restrict__ dw, const float* __restrict__ db,
    const float* __restrict__ lw, const float* __restrict__ lb,
    unsigned short* __restrict__ y) {
    int row = blockIdx.x * 4 + (threadIdx.x >> 6);
    int lane = threadIdx.x & 63;
    float* gp = grid + (size_t)row * D + lane * 4;
    float4 v = *(float4*)gp;
    if (DENS) {
        float de = dens[row];
        float4 w4 = *(const float4*)(dw + lane * 4);
        float4 b4 = *(const float4*)(db + lane * 4);
        v.x += de * w4.x + b4.x; v.y += de * w4.y + b4.y;
        v.z += de * w4.z + b4.z; v.w += de * w4.w + b4.w;
        *(float4*)gp = v;
    }
    float s = v.x + v.y + v.z + v.w;
    #pragma unroll
    for (int o = 32; o > 0; o >>= 1) s += __shfl_xor(s, o);
    float mean = s * (1.f / D);
    float cx = v.x - mean, cy = v.y - mean, cz = v.z - mean, cw = v.w - mean;
    float q = cx * cx + cy * cy + cz * cz + cw * cw;
    #pragma unroll
    for (int o = 32; o > 0; o >>= 1) q += __shfl_xor(q, o);
    float inv = rsqrtf(q * (1.f / D) + 1e-5f);
    float4 lwv = *(const float4*)(lw + lane * 4);
    float4 lbv = *(const float4*)(lb + lane * 4);
    ushort4 o4;
    o4.x = f2bf(cx * inv * lwv.x + lbv.x);
    o4.y = f2bf(cy * inv * lwv.y + lbv.y);
    o4.z = f2bf(cz * inv * lwv.z + lbv.z);
    o4.w = f2bf(cw * inv * lwv.w + lbv.w);
    *(ushort4*)(y + (size_t)row * D + lane * 4) = o4;
}

// ================= GEMM core (BM=64): C[M,N] = A[M,K] @ Wt[N,K]^T + bias =================
// BM=64, BN=64, BK=64, double-buffered LDS. Used for the small KV projection.
// LDS bank-balance swizzle (both-sides-or-neither): staging lane loads global 16B
// column-group (tid&3)^((tid>>3)&3); reads XOR q4 with ((lr>>1)&3).
template <int GELU, int ACCUM, int OBF, int TFPH, int STBF, int KVT = 0>
__device__ __forceinline__ void gemm_core(
    const unsigned short* __restrict__ A, const unsigned short* __restrict__ Wt,
    const float* __restrict__ bias, void* __restrict__ Cv,
    int M, int K, int Nn, int bn, int bm,
    const float* __restrict__ hw, unsigned short* __restrict__ Xb, float scale,
    unsigned short* As, unsigned short* Bs) {
    int tid = threadIdx.x;
    int wave = tid >> 6, lane = tid & 63;
    int q4 = lane >> 4, lr = lane & 15;
    int wn = wave * 16;
    int srow = tid >> 2;
    int sk8 = ((tid & 3) ^ ((tid >> 3) & 3)) * 8;   // swizzled source column-group
    const unsigned short* Ap  = A  + (size_t)(bm + srow) * K + sk8;
    const unsigned short* Bp0 = Wt + (size_t)(bn + srow) * K + sk8;
    unsigned short* AsD = As + tid * 8;
    unsigned short* BsD = Bs + tid * 8;
    int q4x = (q4 ^ ((lr >> 1) & 3)) * 8;           // swizzled read column-group
    f32x4 acc[4] = {};

    gl2lds16(Ap,       AsD);
    gl2lds16(Ap + 32,  AsD + 2048);
    gl2lds16(Bp0,      BsD);
    gl2lds16(Bp0 + 32, BsD + 2048);

    int nk = K >> 6;
    for (int ki = 0; ki < nk; ki++) {
        __syncthreads();
        if (ki + 1 < nk) {
            int k0 = (ki + 1) << 6;
            int nb = ((ki + 1) & 1) * 4096;
            gl2lds16(Ap + k0,       AsD + nb);
            gl2lds16(Ap + k0 + 32,  AsD + nb + 2048);
            gl2lds16(Bp0 + k0,      BsD + nb);
            gl2lds16(Bp0 + k0 + 32, BsD + nb + 2048);
        }
        int cb = (ki & 1) * 4096;
        #pragma unroll
        for (int ks = 0; ks < 2; ks++) {
            bf16x8 af[4], bf;
            #pragma unroll
            for (int i = 0; i < 4; i++)
                af[i] = *(const bf16x8*)&As[cb + ks * 2048 + (i * 16 + lr) * 32 + q4x];
            bf = *(const bf16x8*)&Bs[cb + ks * 2048 + (wn + lr) * 32 + q4x];
            #pragma unroll
            for (int i = 0; i < 4; i++)
                acc[i] = __builtin_amdgcn_mfma_f32_16x16x32_bf16(af[i], bf, acc[i], 0, 0, 0);
        }
    }

    if (KVT) {
        int gc = bn + wn + lr;
        float bv = bias[gc];
        bool isV = gc >= 256;
        #pragma unroll
        for (int i = 0; i < 4; i++) {
            #pragma unroll
            for (int r = 0; r < 4; r++) {
                int gr = bm + i * 16 + q4 * 4 + r;
                if (gr < MSRC) {
                    float v = acc[i][r] + bv;
                    int bb = gr / NS;
                    int tok = gr - bb * NS;
                    if (!isV) {
                        int h = gc >> 5, dh = gc & 31;
                        // permuted K storage: within chunk, token t32 stored at
                        // kk = ((t32&1)<<4) | ((t32>>3)<<2) | ((t32>>1)&3)
                        int t32 = tok & 31;
                        int kkp = ((t32 & 1) << 4) | ((t32 >> 3) << 2) | ((t32 >> 1) & 3);
                        int tokP = (tok & ~31) | kkp;
                        ((unsigned short*)Cv)[(((size_t)(bb * 8 + h) * 544) + tokP) * 32 + dh] = f2bf(v);
                    } else {
                        int gcv = gc - 256;
                        int h = gcv >> 5, dh = gcv & 31;
                        int c = tok >> 5, t32 = tok & 31;
                        Xb[((((size_t)(bb * 8 + h) * 17 + c) * 32 + dh)) * 32 + t32] = f2bf(v);
                    }
                }
            }
        }
        return;
    }

    int gc = bn + wn + lr;
    float bv = bias[gc];
    #pragma unroll
    for (int i = 0; i < 4; i++) {
        #pragma unroll
        for (int r = 0; r < 4; r++) {
            int gr = bm + i * 16 + q4 * 4 + r;
            if (gr < M) {
                float v = (acc[i][r] + bv) * scale;
                if (GELU) v = gelu_f(v);
                size_t idx = (size_t)gr * Nn + gc;
                if (OBF) {
                    ((unsigned short*)Cv)[idx] = f2bf(v);
                } else if (ACCUM) {
                    float nv = ((float*)Cv)[idx] + v;
                    ((float*)Cv)[idx] = nv;
                    if (STBF) Xb[idx] = f2bf(nv);
                } else {
                    ((float*)Cv)[idx] = v;
                }
            }
        }
    }
}

// ================= GEMM BM=128 core: BK=64, double-buffered LDS (48 KB) =================
// Same bank swizzle as gemm_core; per wave 8 row-frags x 1 col-frag.
template <int GELU, int ACCUM, int OBF, int STBF>
__device__ __forceinline__ void gemm128_core(
    const unsigned short* __restrict__ A, const unsigned short* __restrict__ Wt,
    const float* __restrict__ bias, void* __restrict__ Cv,
    int K, int Nn, int bn, int bm, float scale, unsigned short* __restrict__ Xb,
    unsigned short* As, unsigned short* Bs) {
    int tid = threadIdx.x;
    int wave = tid >> 6, lane = tid & 63;
    int q4 = lane >> 4, lr = lane & 15;
    int wn = wave * 16;
    int srow = tid >> 2;
    int sk8 = ((tid & 3) ^ ((tid >> 3) & 3)) * 8;   // swizzled source column-group
    const unsigned short* Ap  = A + (size_t)(bm + srow) * K + sk8;        // rows 0..63
    const unsigned short* Ap2 = Ap + (size_t)64 * K;                      // rows 64..127
    const unsigned short* Bp  = Wt + (size_t)(bn + srow) * K + sk8;
    unsigned short* AsD = As + tid * 8;
    unsigned short* BsD = Bs + tid * 8;
    int q4x = (q4 ^ ((lr >> 1) & 3)) * 8;           // swizzled read column-group
    f32x4 acc[8] = {};

    gl2lds16(Ap,        AsD);            // rows 0-63,   ks0
    gl2lds16(Ap2,       AsD + 2048);     // rows 64-127, ks0
    gl2lds16(Ap + 32,   AsD + 4096);     // rows 0-63,   ks1
    gl2lds16(Ap2 + 32,  AsD + 6144);     // rows 64-127, ks1
    gl2lds16(Bp,        BsD);
    gl2lds16(Bp + 32,   BsD + 2048);

    int nk = K >> 6;
    for (int ki = 0; ki < nk; ki++) {
        __syncthreads();
        if (ki + 1 < nk) {
            int k0 = (ki + 1) << 6;
            int nbA = ((ki + 1) & 1) * 8192;
            int nbB = ((ki + 1) & 1) * 4096;
            gl2lds16(Ap + k0,        AsD + nbA);
            gl2lds16(Ap2 + k0,       AsD + nbA + 2048);
            gl2lds16(Ap + k0 + 32,   AsD + nbA + 4096);
            gl2lds16(Ap2 + k0 + 32,  AsD + nbA + 6144);
            gl2lds16(Bp + k0,        BsD + nbB);
            gl2lds16(Bp + k0 + 32,   BsD + nbB + 2048);
        }
        int cbA = (ki & 1) * 8192, cbB = (ki & 1) * 4096;
        #pragma unroll
        for (int ks = 0; ks < 2; ks++) {
            bf16x8 bf = *(const bf16x8*)&Bs[cbB + ks * 2048 + (wn + lr) * 32 + q4x];
            #pragma unroll
            for (int i = 0; i < 8; i++) {
                bf16x8 af = *(const bf16x8*)&As[cbA + ks * 4096 + (i * 16 + lr) * 32 + q4x];
                acc[i] = __builtin_amdgcn_mfma_f32_16x16x32_bf16(af, bf, acc[i], 0, 0, 0);
            }
        }
    }

    int gc = bn + wn + lr;
    float bv = bias[gc];
    #pragma unroll
    for (int i = 0; i < 8; i++) {
        #pragma unroll
        for (int r = 0; r < 4; r++) {
            int gr = bm + i * 16 + q4 * 4 + r;
            float v = (acc[i][r] + bv) * scale;
            if (GELU) v = gelu_f(v);
            size_t idx = (size_t)gr * Nn + gc;
            if (OBF) {
                ((unsigned short*)Cv)[idx] = f2bf(v);
            } else if (ACCUM) {
                float nv = ((float*)Cv)[idx] + v;
                ((float*)Cv)[idx] = nv;
                if (STBF) Xb[idx] = f2bf(nv);
            } else {
                ((float*)Cv)[idx] = v;
            }
        }
    }
}

// 1D grid + bijective XCD swizzle (nwg % 8 == 0): each XCD owns a contiguous chunk of
// bm-stripes so the A panel shared by the nx bn-blocks of a stripe is fetched by ONE
// XCD's L2 instead of all 8.
template <int GELU, int ACCUM, int OBF, int STBF>
__global__ __launch_bounds__(256) void gemm128_k(
    const unsigned short* __restrict__ A, const unsigned short* __restrict__ Wt,
    const float* __restrict__ bias, void* __restrict__ Cv,
    int M, int K, int Nn, int nx, float scale, unsigned short* __restrict__ Xb) {
    __shared__ unsigned short As[16384];
    __shared__ unsigned short Bs[8192];
    int nwg = gridDim.x;
    int bid = blockIdx.x;
    int wgid = (bid & 7) * (nwg >> 3) + (bid >> 3);   // XCD-chunked remap (bijective)
    int bn = (wgid % nx) * 64;
    int bm = (wgid / nx) * 128;
    gemm128_core<GELU, ACCUM, OBF, STBF>(A, Wt, bias, Cv, K, Nn, bn, bm, scale, Xb, As, Bs);
}

// ================= fused Q (BM=128) + KV (BM=64) projections, one launch ==============
// Blocks 0..511: Q with XCD swizzle (identical to gemm128_k<0,0,1,0> nx=4, nwg=512).
// Blocks 512..783: KV projection (8 bn x 34 bm), same math as the old kv_k.
__global__ __launch_bounds__(256) void qkv128_k(
    const unsigned short* __restrict__ xbf, const unsigned short* __restrict__ wqT,
    const float* __restrict__ bq, unsigned short* __restrict__ qbf,
    const unsigned short* __restrict__ srcbf, const unsigned short* __restrict__ kvT,
    const float* __restrict__ kvb, unsigned short* __restrict__ khd,
    unsigned short* __restrict__ vch) {
    __shared__ unsigned short As[16384];
    __shared__ unsigned short Bs[8192];
    int bid = blockIdx.x;
    if (bid < 512) {
        int wgid = (bid & 7) * 64 + (bid >> 3);
        int bn = (wgid & 3) * 64;
        int bm = (wgid >> 2) * 128;
        gemm128_core<0, 0, 1, 0>(xbf, wqT, bq, qbf, D, D, bn, bm,
                                 ISQ * LOG2E, nullptr, As, Bs);
    } else {
        int idx = bid - 512;          // 0..271 = 8 bn x 34 bm
        gemm_core<0, 0, 1, 0, 0, 1>(srcbf, kvT, kvb, khd, MSRC, D, 512,
                                    (idx & 7) * 64, (idx >> 3) * 64, nullptr, vch, 1.f, As, Bs);
    }
}

// ================= tfp head GEMM, BM=128: per-task weights + gelu + head-dot epilogue ========
// Same 1D grid + XCD swizzle as gemm128_k (nx = 4).
__global__ __launch_bounds__(256) void tfp128_k(
    const unsigned short* __restrict__ A, const unsigned short* __restrict__ Wt0,
    const float* __restrict__ bias0, float* __restrict__ Cv,
    const int* __restrict__ task_id, const float* __restrict__ hw) {
    __shared__ unsigned short As[16384];
    __shared__ unsigned short Bs[8192];
    int nwg = gridDim.x;
    int bid = blockIdx.x;
    int wgid = (bid & 7) * (nwg >> 3) + (bid >> 3);
    int bn = (wgid & 3) * 64;
    int bm = (wgid >> 2) * 128;
    int tid = threadIdx.x;
    int wave = tid >> 6, lane = tid & 63;
    int q4 = lane >> 4, lr = lane & 15;
    int wn = wave * 16;
    int t = task_id[bm >> 12];
    const unsigned short* Wt = Wt0 + (size_t)t * D * D;
    const float* bias = bias0 + t * D;
    int srow = tid >> 2;
    int sk8 = ((tid & 3) ^ ((tid >> 3) & 3)) * 8;
    const unsigned short* Ap  = A + (size_t)(bm + srow) * D + sk8;
    const unsigned short* Ap2 = Ap + (size_t)64 * D;
    const unsigned short* Bp  = Wt + (size_t)(bn + srow) * D + sk8;
    unsigned short* AsD = As + tid * 8;
    unsigned short* BsD = Bs + tid * 8;
    int q4x = (q4 ^ ((lr >> 1) & 3)) * 8;
    f32x4 acc[8] = {};

    gl2lds16(Ap,        AsD);
    gl2lds16(Ap2,       AsD + 2048);
    gl2lds16(Ap + 32,   AsD + 4096);
    gl2lds16(Ap2 + 32,  AsD + 6144);
    gl2lds16(Bp,        BsD);
    gl2lds16(Bp + 32,   BsD + 2048);

    int nk = D >> 6;
    for (int ki = 0; ki < nk; ki++) {
        __syncthreads();
        if (ki + 1 < nk) {
            int k0 = (ki + 1) << 6;
            int nbA = ((ki + 1) & 1) * 8192;
            int nbB = ((ki + 1) & 1) * 4096;
            gl2lds16(Ap + k0,        AsD + nbA);
            gl2lds16(Ap2 + k0,       AsD + nbA + 2048);
            gl2lds16(Ap + k0 + 32,   AsD + nbA + 4096);
            gl2lds16(Ap2 + k0 + 32,  AsD + nbA + 6144);
            gl2lds16(Bp + k0,        BsD + nbB);
            gl2lds16(Bp + k0 + 32,   BsD + nbB + 2048);
        }
        int cbA = (ki & 1) * 8192, cbB = (ki & 1) * 4096;
        #pragma unroll
        for (int ks = 0; ks < 2; ks++) {
            bf16x8 bf = *(const bf16x8*)&Bs[cbB + ks * 2048 + (wn + lr) * 32 + q4x];
            #pragma unroll
            for (int i = 0; i < 8; i++) {
                bf16x8 af = *(const bf16x8*)&As[cbA + ks * 4096 + (i * 16 + lr) * 32 + q4x];
                acc[i] = __builtin_amdgcn_mfma_f32_16x16x32_bf16(af, bf, acc[i], 0, 0, 0);
            }
        }
    }

    int gc = bn + wn + lr;
    float bv = bias[gc];
    float hv = hw[gc];
    #pragma unroll
    for (int i = 0; i < 8; i++) {
        #pragma unroll
        for (int r = 0; r < 4; r++) {
            float s = gelu_f(acc[i][r] + bv) * hv;
            s += __shfl_xor(s, 1); s += __shfl_xor(s, 2);
            s += __shfl_xor(s, 4); s += __shfl_xor(s, 8);
            if (lr == 0)
                atomicAdd(Cv + (bm + i * 16 + q4 * 4 + r), s);
        }
    }
}

// ================= MFMA flash cross-attention: qt-PAIR per block, shared K/V =========
// S' = K Q^T (query=col, q pre-scaled isq*log2e), p = exp2(s - dist'); O^T = V^T P'.
// K chunk rows are permuted so the S' C/D layout IS the PV B-operand layout (no cross-lane).
// One block = (b, h, qt-pair): rows qt0=2*qp and qt1=qt0+1 SHARE the K/V fragments
// (K/V L2 traffic per query halves vs per-qt blocks) and share dx^2 in DIST; two
// independent QK->exp2->PV chains per wave double ILP to offset the TLP drop.
// 2-deep register prefetch, stages X/Y.
__global__ __launch_bounds__(256) void attn_mfma(
    const unsigned short* __restrict__ qb,
    const unsigned short* __restrict__ khd,
    const unsigned short* __restrict__ vch,
    const float* __restrict__ sxy,
    unsigned short* __restrict__ out)
{
    __shared__ float2 sxys[NSP];
    int bid = blockIdx.x;                    // b*256 + h*32 + qp
    int qp = bid & 31, h = (bid >> 5) & 7, b = bid >> 8;
    int qt0 = qp * 2;
    int tid = threadIdx.x, wave = tid >> 6, lane = tid & 63;
    int q4 = lane >> 4, lr = lane & 15;

    int cell0 = qt0 * 64 + wave * 16 + lr;           // query grid cell, row qt0
    size_t qrow0 = (size_t)(b * KK + cell0);
    size_t qrow1 = qrow0 + 64;                       // row qt0+1, same x
    bf16x8 qfA = *(const bf16x8*)(qb + qrow0 * D + h * DH + q4 * 8);
    bf16x8 qfB = *(const bf16x8*)(qb + qrow1 * D + h * DH + q4 * 8);
    const unsigned short* kp0 = khd + ((size_t)(b * 8 + h) * 544) * 32 + lr * 32 + q4 * 8;
    const unsigned short* vb0 = vch + ((size_t)(b * 8 + h) * 17) * 1024 + lr * 32 + q4 * 8;

    float lla0 = 0.f, lla1 = 0.f, llb0 = 0.f, llb1 = 0.f;
    f32x4 o0a = {0.f, 0.f, 0.f, 0.f}, o1a = {0.f, 0.f, 0.f, 0.f};
    f32x4 o0b = {0.f, 0.f, 0.f, 0.f}, o1b = {0.f, 0.f, 0.f, 0.f};

    bf16x8 k0X, k1X, v0X, v1X, k0Y, k1Y, v0Y, v1Y;
    f32x4 d0X, d1X, d0Y, d1Y;    // dist*log2e, row qt0 (slots: d0 = even tokens, d1 = odd)
    f32x4 e0X, e1X, e0Y, e1Y;    // dist*log2e, row qt1

#define LDK(S, c) { size_t co = (size_t)(c) * 1024; \
    k0##S = *(const bf16x8*)(kp0 + co); k1##S = *(const bf16x8*)(kp0 + co + 512); }
#define LDV(S, c) { size_t co = (size_t)(c) * 1024; \
    v0##S = *(const bf16x8*)(vb0 + co); v1##S = *(const bf16x8*)(vb0 + co + 512); }

    // issue global K/V prefetch before LDS staging so HBM latency overlaps it
    LDK(X, 0); LDV(X, 0);
    LDK(Y, 1); LDV(Y, 1);

    // stage (x*log2e, y*log2e); pads -> huge dist -> p = 0
    const float2* sb = (const float2*)(sxy + 2 * (size_t)b * NS);
    for (int i = tid; i < NSP; i += 256) {
        float2 v = (i < NS) ? sb[i] : make_float2(1.e4f, 1.e4f);
        sxys[i] = make_float2(v.x * LOG2E, v.y * LOG2E);
    }
    __syncthreads();

    int qi = wave * 16 + lr;                         // query x-cell (shared by both rows)
    float gxp  = (qi + 0.5f) * (1.f / 64.f) * LOG2E;
    float gy0p = (qt0 + 0.5f) * (1.f / 64.f) * LOG2E;
    float gy1p = (qt0 + 1.5f) * (1.f / 64.f) * LOG2E;
    const float2* spf = &sxys[q4 * 8];

    // dist for both rows; dx^2 shared (same query x)
#define DIST2(xx, yy, dq0, dq1) { float dx_ = gxp - (xx); float dx2_ = dx_ * dx_; \
    float dy0_ = gy0p - (yy); dq0 = __builtin_amdgcn_sqrtf(__builtin_fmaf(dy0_, dy0_, dx2_)); \
    float dy1_ = gy1p - (yy); dq1 = __builtin_amdgcn_sqrtf(__builtin_fmaf(dy1_, dy1_, dx2_)); }
    // tokens for this lane in chunk c: c*32 + q4*8 + {0..7}; slot r of s0 uses token 2r,
    // slot r of s1 uses token 2r+1 (the K permutation).
#define LDB(S, c) { const float4* p4_ = (const float4*)(spf + (size_t)(c) * 32); \
    float4 a0_ = p4_[0], a1_ = p4_[1], a2_ = p4_[2], a3_ = p4_[3]; \
    DIST2(a0_.x, a0_.y, d0##S[0], e0##S[0]); DIST2(a0_.z, a0_.w, d1##S[0], e1##S[0]); \
    DIST2(a1_.x, a1_.y, d0##S[1], e0##S[1]); DIST2(a1_.z, a1_.w, d1##S[1], e1##S[1]); \
    DIST2(a2_.x, a2_.y, d0##S[2], e0##S[2]); DIST2(a2_.z, a2_.w, d1##S[2], e1##S[2]); \
    DIST2(a3_.x, a3_.y, d0##S[3], e0##S[3]); DIST2(a3_.z, a3_.w, d1##S[3], e1##S[3]); }

    LDB(X, 0); LDB(Y, 1);

#define BODY(S, cp) { \
    f32x4 s0a = {0.f, 0.f, 0.f, 0.f}, s1a = {0.f, 0.f, 0.f, 0.f}; \
    f32x4 s0b = {0.f, 0.f, 0.f, 0.f}, s1b = {0.f, 0.f, 0.f, 0.f}; \
    s0a = __builtin_amdgcn_mfma_f32_16x16x32_bf16(k0##S, qfA, s0a, 0, 0, 0); \
    s1a = __builtin_amdgcn_mfma_f32_16x16x32_bf16(k1##S, qfA, s1a, 0, 0, 0); \
    s0b = __builtin_amdgcn_mfma_f32_16x16x32_bf16(k0##S, qfB, s0b, 0, 0, 0); \
    s1b = __builtin_amdgcn_mfma_f32_16x16x32_bf16(k1##S, qfB, s1b, 0, 0, 0); \
    LDK(S, cp); \
    float p0a[4], p1a[4], p0b[4], p1b[4]; \
    p0a[0] = __builtin_amdgcn_exp2f(s0a[0] - d0##S[0]); \
    p0a[1] = __builtin_amdgcn_exp2f(s0a[1] - d0##S[1]); \
    p0a[2] = __builtin_amdgcn_exp2f(s0a[2] - d0##S[2]); \
    p0a[3] = __builtin_amdgcn_exp2f(s0a[3] - d0##S[3]); \
    p1a[0] = __builtin_amdgcn_exp2f(s1a[0] - d1##S[0]); \
    p1a[1] = __builtin_amdgcn_exp2f(s1a[1] - d1##S[1]); \
    p1a[2] = __builtin_amdgcn_exp2f(s1a[2] - d1##S[2]); \
    p1a[3] = __builtin_amdgcn_exp2f(s1a[3] - d1##S[3]); \
    p0b[0] = __builtin_amdgcn_exp2f(s0b[0] - e0##S[0]); \
    p0b[1] = __builtin_amdgcn_exp2f(s0b[1] - e0##S[1]); \
    p0b[2] = __builtin_amdgcn_exp2f(s0b[2] - e0##S[2]); \
    p0b[3] = __builtin_amdgcn_exp2f(s0b[3] - e0##S[3]); \
    p1b[0] = __builtin_amdgcn_exp2f(s1b[0] - e1##S[0]); \
    p1b[1] = __builtin_amdgcn_exp2f(s1b[1] - e1##S[1]); \
    p1b[2] = __builtin_amdgcn_exp2f(s1b[2] - e1##S[2]); \
    p1b[3] = __builtin_amdgcn_exp2f(s1b[3] - e1##S[3]); \
    LDB(S, cp); \
    lla0 += (p0a[0] + p0a[1]) + (p0a[2] + p0a[3]); \
    lla1 += (p1a[0] + p1a[1]) + (p1a[2] + p1a[3]); \
    llb0 += (p0b[0] + p0b[1]) + (p0b[2] + p0b[3]); \
    llb1 += (p1b[0] + p1b[1]) + (p1b[2] + p1b[3]); \
    union { unsigned u[4]; bf16x8 v; } pua, pub; \
    pua.u[0] = cvtpk(p0a[0], p1a[0]); \
    pua.u[1] = cvtpk(p0a[1], p1a[1]); \
    pua.u[2] = cvtpk(p0a[2], p1a[2]); \
    pua.u[3] = cvtpk(p0a[3], p1a[3]); \
    pub.u[0] = cvtpk(p0b[0], p1b[0]); \
    pub.u[1] = cvtpk(p0b[1], p1b[1]); \
    pub.u[2] = cvtpk(p0b[2], p1b[2]); \
    pub.u[3] = cvtpk(p0b[3], p1b[3]); \
    o0a = __builtin_amdgcn_mfma_f32_16x16x32_bf16(v0##S, pua.v, o0a, 0, 0, 0); \
    o1a = __builtin_amdgcn_mfma_f32_16x16x32_bf16(v1##S, pua.v, o1a, 0, 0, 0); \
    o0b = __builtin_amdgcn_mfma_f32_16x16x32_bf16(v0##S, pub.v, o0b, 0, 0, 0); \
    o1b = __builtin_amdgcn_mfma_f32_16x16x32_bf16(v1##S, pub.v, o1b, 0, 0, 0); \
    LDV(S, cp); \
}

    for (int c = 0; c < 16; c += 2) {
        int cpX = c + 2;                       // c <= 14 -> cpX <= 16, always valid
        int cpY = (c + 3 > 16) ? 16 : c + 3;   // clamp; redundant reload is harmless
        BODY(X, cpX);
        BODY(Y, cpY);
    }
    BODY(X, 16);   // chunk 16 tail; trailing prefetch is dead and DCE'd

#undef BODY
#undef LDB
#undef DIST2
#undef LDK
#undef LDV

    float lla = lla0 + lla1;
    lla += __shfl_xor(lla, 16);
    lla += __shfl_xor(lla, 32);
    float inva = 1.f / lla;
    float llb = llb0 + llb1;
    llb += __shfl_xor(llb, 16);
    llb += __shfl_xor(llb, 32);
    float invb = 1.f / llb;
    uint2 sa0, sa1, sb0, sb1;
    sa0.x = cvtpk(o0a[0] * inva, o0a[1] * inva);
    sa0.y = cvtpk(o0a[2] * inva, o0a[3] * inva);
    sa1.x = cvtpk(o1a[0] * inva, o1a[1] * inva);
    sa1.y = cvtpk(o1a[2] * inva, o1a[3] * inva);
    sb0.x = cvtpk(o0b[0] * invb, o0b[1] * invb);
    sb0.y = cvtpk(o0b[2] * invb, o0b[3] * invb);
    sb1.x = cvtpk(o1b[0] * invb, o1b[1] * invb);
    sb1.y = cvtpk(o1b[2] * invb, o1b[3] * invb);
    *(uint2*)(out + qrow0 * D + h * DH + q4 * 4) = sa0;
    *(uint2*)(out + qrow0 * D + h * DH + 16 + q4 * 4) = sa1;
    *(uint2*)(out + qrow1 * D + h * DH + q4 * 4) = sb0;
    *(uint2*)(out + qrow1 * D + h * DH + 16 + q4 * 4) = sb1;
}

extern "C" void kernel_launch(void* const* d_in, const int* in_sizes, int n_in,
                              void* d_out, int out_size, void* d_ws, size_t ws_size,
                              hipStream_t stream) {
    const float* meas_xy = (const float*)d_in[0];
    const float* meas_v  = (const float*)d_in[1];
    const float* bs_xy   = (const float*)d_in[2];
    const int*   task_id = (const int*)d_in[3];
    const float* city    = (const float*)d_in[4];
    const float* mp_w1 = (const float*)d_in[5];  const float* mp_b1 = (const float*)d_in[6];
    const float* mp_w2 = (const float*)d_in[7];  const float* mp_b2 = (const float*)d_in[8];
    const float* bp_w1 = (const float*)d_in[9];  const float* bp_b1 = (const float*)d_in[10];
    const float* bp_w2 = (const float*)d_in[11]; const float* bp_b2 = (const float*)d_in[12];
    const float* env_w1 = (const float*)d_in[13]; const float* env_b1 = (const float*)d_in[14];
    const float* env_w2 = (const float*)d_in[15]; const float* env_b2 = (const float*)d_in[16];
    const float* env_w3 = (const float*)d_in[17]; const float* env_b3 = (const float*)d_in[18];
    const float* task_emb = (const float*)d_in[19];
    const float* tp_w = (const float*)d_in[20]; const float* tp_b = (const float*)d_in[21];
    const float* grid_pos = (const float*)d_in[22];
    const float* dens_w = (const float*)d_in[23]; const float* dens_b = (const float*)d_in[24];
    const float* ln1_w = (const float*)d_in[25]; const float* ln1_b = (const float*)d_in[26];
    const float* wq = (const float*)d_in[27]; const float* bq = (const float*)d_in[28];
    const float* wk = (const float*)d_in[29]; const float* bk = (const float*)d_in[30];
    const float* wv = (const float*)d_in[31]; const float* bv = (const float*)d_in[32];
    const float* wo = (const float*)d_in[33]; const float* bo = (const float*)d_in[34];
    const float* ln2_w = (const float*)d_in[35]; const float* ln2_b = (const float*)d_in[36];
    const float* ff_w1 = (const float*)d_in[37]; const float* ff_b1 = (const float*)d_in[38];
    const float* ff_w2 = (const float*)d_in[39]; const float* ff_b2 = (const float*)d_in[40];
    const float* tfp_w = (const float*)d_in[41]; const float* tfp_b = (const float*)d_in[42];
    const float* head_w = (const float*)d_in[43]; const float* head_b = (const float*)d_in[44];
    float* out = (float*)d_out;

    float* ws = (float*)d_ws;
    size_t off = 0;
    float* src_xy = ws + off; off += (size_t)B * NS * 2 + 128;
    float* dens   = ws + off; off += (size_t)B * KK;
    float* tvec   = ws + off; off += (size_t)B * D;
    float* h1     = ws + off; off += (size_t)B * EC * KK;
    float* grid   = ws + off; off += (size_t)B * KK * D;
    unsigned short* srcbf = (unsigned short*)(ws + off); off += (size_t)MSRCP * D / 2;
    unsigned short* khd   = (unsigned short*)(ws + off); off += (size_t)B * 8 * 544 * 32 / 2;
    unsigned short* vch   = (unsigned short*)(ws + off); off += (size_t)B * 8 * 17 * 1024 / 2;
    float* qreg   = ws + off; off += (size_t)B * KK * D / 2;   // qbf; hosts h2 f32 early
    unsigned short* qbf = (unsigned short*)qreg;
    float* h2     = qreg;
    unsigned short* xbf    = (unsigned short*)(ws + off); off += (size_t)B * KK * D / 2;
    unsigned short* attnbf = (unsigned short*)(ws + off); off += (size_t)B * KK * D / 2;
    unsigned short* hidbf  = (unsigned short*)(ws + off); off += (size_t)B * KK * DFF / 2;    // 32 MB
    unsigned short* wqT  = (unsigned short*)(ws + off); off += (size_t)LYR * D * D / 2;
    unsigned short* kvT  = (unsigned short*)(ws + off); off += (size_t)LYR * 512 * D / 2;
    unsigned short* woT  = (unsigned short*)(ws + off); off += (size_t)LYR * D * D / 2;
    unsigned short* ff1T = (unsigned short*)(ws + off); off += (size_t)LYR * D * DFF / 2;
    unsigned short* ff2T = (unsigned short*)(ws + off); off += (size_t)LYR * DFF * D / 2;
    unsigned short* tfpT = (unsigned short*)(ws + off); off += (size_t)T * D * D / 2;
    float* kvbias = ws + off; off += (size_t)LYR * 512;
    (void)ws_size; (void)n_in; (void)in_sizes; (void)out_size;

    const int M = B * KK;       // 16384

    pre1_k<<<6116, 256, 0, stream>>>(
        wq, wk, wv, wo, ff_w1, ff_w2, tfp_w, bk, bv,
        wqT, kvT, woT, ff1T, ff2T, tfpT, kvbias,
        meas_xy, meas_v, bs_xy, mp_w1, mp_b1, mp_w2, mp_b2,
        bp_w1, bp_b1, bp_w2, bp_b2, srcbf, src_xy,
        dens, city, env_w1, env_b1, h1,
        task_emb, task_id, tp_w, tp_b, tvec, khd, vch);
    conv2_k<<<512, 256, 0, stream>>>(h1, env_w2, env_b2, h2);
    pre2_k<<<2112, 256, 0, stream>>>(h2, env_w3, env_b3, grid_pos, tvec, grid,
                                     out, head_b);

    for (int l = 0; l < LYR; l++) {
        dens_ln_k<1><<<M / 4, 256, 0, stream>>>(grid, dens, dens_w + l * D, dens_b + l * D,
                                                ln1_w + l * D, ln1_b + l * D, xbf);
        qkv128_k<<<784, 256, 0, stream>>>(
            xbf, wqT + (size_t)l * D * D, bq + l * D, qbf,
            srcbf, kvT + (size_t)l * 512 * D, kvbias + l * 512, khd, vch);
        attn_mfma<<<B * NH * 32, 256, 0, stream>>>(qbf, khd, vch, src_xy, attnbf);
        gemm128_k<0, 1, 0, 0><<<512, 256, 0, stream>>>(
            attnbf, woT + (size_t)l * D * D, bo + l * D, grid, M, D, D, 4, 1.f, nullptr);
        dens_ln_k<0><<<M / 4, 256, 0, stream>>>(grid, nullptr, nullptr, nullptr,
                                                ln2_w + l * D, ln2_b + l * D, xbf);
        gemm128_k<1, 0, 1, 0><<<2048, 256, 0, stream>>>(
            xbf, ff1T + (size_t)l * D * DFF, ff_b1 + l * DFF, hidbf, M, D, DFF, 16, 1.f, nullptr);
        if (l == 0) {
            gemm128_k<0, 1, 0, 0><<<512, 256, 0, stream>>>(
                hidbf, ff2T + (size_t)l * DFF * D, ff_b2 + l * D, grid, M, DFF, D, 4, 1.f, nullptr);
        } else {
            gemm128_k<0, 1, 0, 1><<<512, 256, 0, stream>>>(
                hidbf, ff2T + (size_t)l * DFF * D, ff_b2 + l * D, grid, M, DFF, D, 4, 1.f, xbf);
        }
    }
    tfp128_k<<<512, 256, 0, stream>>>(xbf, tfpT, tfp_b, out, task_id, head_w);
}

// Round 12
// 475.648 us; speedup vs baseline: 1.0235x; 1.0090x over previous
//
#include <hip/hip_runtime.h>
#include <hip/hip_bf16.h>
#include <math.h>

#define D 256
#define NH 8
#define DH 32
#define LYR 2
#define G 64
#define KK 4096
#define T 4
#define EC 32
#define B 4
#define N 512
#define CITY 256
#define DFF 1024
#define NS 513    // N + 1 bs token
#define NSP 544   // 17 * 32 padded token count
#define MSRC 2052 // B * NS
#define MSRCP 2176 // padded to 34*64
#define ISQ 0.17677669529663687f
#define LOG2E 1.4426950408889634f

typedef short bf16x8 __attribute__((ext_vector_type(8)));
typedef float f32x4 __attribute__((ext_vector_type(4)));

// gelu via exact identity 0.5*(1+tanh(u)) == sigmoid(2u); exp2+rcp, ~7 VALU vs libm tanhf
__device__ __forceinline__ float gelu_f(float x) {
    const float c2 = 2.f * 0.7978845608028654f * LOG2E;  // 2*c*log2e
    float u = x + 0.044715f * x * x * x;
    float e = __builtin_amdgcn_exp2f(-c2 * u);
    return x * __builtin_amdgcn_rcpf(1.f + e);
}

__device__ __forceinline__ unsigned short f2bf(float f) {
    unsigned int u = __float_as_uint(f);
    unsigned int r = (u + 0x7FFFu + ((u >> 16) & 1u)) >> 16;
    return (unsigned short)r;
}

__device__ __forceinline__ float bf2f(unsigned short u) {
    return __uint_as_float((unsigned)u << 16);
}

__device__ __forceinline__ unsigned cvtpk(float a, float b) {
    unsigned r;
    asm("v_cvt_pk_bf16_f32 %0, %1, %2" : "=v"(r) : "v"(a), "v"(b));
    return r;
}

__device__ __forceinline__ void gl2lds16(const unsigned short* g, unsigned short* l) {
    __builtin_amdgcn_global_load_lds(
        (const __attribute__((address_space(1))) unsigned int*)g,
        (__attribute__((address_space(3))) unsigned int*)l, 16, 0, 0);
}

// ================= pre1: transposes + tok_mlp + density + conv1 + tvec + K/V pad zero ===========
__global__ __launch_bounds__(256) void pre1_k(
    const float* __restrict__ wq, const float* __restrict__ wk,
    const float* __restrict__ wv, const float* __restrict__ wo,
    const float* __restrict__ ff1, const float* __restrict__ ff2,
    const float* __restrict__ tfp,
    const float* __restrict__ bk, const float* __restrict__ bv,
    unsigned short* __restrict__ wqT, unsigned short* __restrict__ kvT,
    unsigned short* __restrict__ woT, unsigned short* __restrict__ ff1T,
    unsigned short* __restrict__ ff2T, unsigned short* __restrict__ tfpT,
    float* __restrict__ kvbias,
    const float* __restrict__ meas_xy, const float* __restrict__ meas_v,
    const float* __restrict__ bs_xy,
    const float* __restrict__ mp_w1, const float* __restrict__ mp_b1,
    const float* __restrict__ mp_w2, const float* __restrict__ mp_b2,
    const float* __restrict__ bp_w1, const float* __restrict__ bp_b1,
    const float* __restrict__ bp_w2, const float* __restrict__ bp_b2,
    unsigned short* __restrict__ srcbf, float* __restrict__ src_xy,
    float* __restrict__ dens,
    const float* __restrict__ city, const float* __restrict__ env_w1,
    const float* __restrict__ env_b1, float* __restrict__ h1,
    const float* __restrict__ task_emb, const int* __restrict__ task_id,
    const float* __restrict__ tp_w, const float* __restrict__ tp_b,
    float* __restrict__ tvec,
    unsigned short* __restrict__ khd, unsigned short* __restrict__ vch)
{
    __shared__ float sh[1088];
    int bx = blockIdx.x;
    int tid = threadIdx.x;
    if (bx < 1792) {
        const float* src; unsigned short* dst;
        int Kd, Nn, nmat, rowOff = 0, t; size_t matStride;
        if (bx < 512) {
            int job = bx >> 7; t = bx & 127;
            Kd = 256; Nn = 256; nmat = 2;
            if (job == 0)      { src = wq; dst = wqT; matStride = 65536; }
            else if (job == 1) { src = wk; dst = kvT; matStride = 131072; }
            else if (job == 2) { src = wv; dst = kvT; matStride = 131072; rowOff = 256; }
            else               { src = wo; dst = woT; matStride = 65536; }
            if ((t & 63) == 0 && job == 1) kvbias[(t >> 6) * 512 + tid] = bk[(t >> 6) * 256 + tid];
            if ((t & 63) == 0 && job == 2) kvbias[(t >> 6) * 512 + 256 + tid] = bv[(t >> 6) * 256 + tid];
        } else if (bx < 1024) { t = bx - 512;  src = ff1; dst = ff1T; Kd = 256;  Nn = 1024; nmat = 2; matStride = 262144; }
        else if (bx < 1536)   { t = bx - 1024; src = ff2; dst = ff2T; Kd = 1024; Nn = 256;  nmat = 2; matStride = 262144; }
        else                  { t = bx - 1536; src = tfp; dst = tfpT; Kd = 256;  Nn = 256;  nmat = 4; matStride = 65536; }
        int tn = Nn / 32, perMat = tn * (Kd / 32);
        int mat = t / perMat;
        int rem = t - mat * perMat;
        int nb = (rem % tn) * 32, kb = (rem / tn) * 32;
        const float* s = src + (size_t)mat * Kd * Nn;
        unsigned short* d = dst + (size_t)mat * matStride;
        float (*tb)[33] = (float (*)[33])sh;
        int tx = tid & 31, ty = tid >> 5;
        #pragma unroll
        for (int i = 0; i < 4; i++)
            tb[ty + i * 8][tx] = s[(size_t)(kb + ty + i * 8) * Nn + nb + tx];
        __syncthreads();
        #pragma unroll
        for (int i = 0; i < 4; i++)
            d[(size_t)(rowOff + nb + ty + i * 8) * Kd + kb + tx] = f2bf(tb[tx][ty + i * 8]);
    } else if (bx < 3968) {
        int id = bx - 1792;
        int dd = tid;
        if (id >= B * N + B) {
            srcbf[(size_t)id * D + dd] = 0;
            return;
        }
        float* hid = sh;
        int row;
        const float *w1, *b1, *w2, *b2;
        float x0, x1, x2 = 0.f;
        int nin;
        if (id < B * N) {
            int b = id >> 9, n = id & 511;
            x0 = meas_xy[(b * N + n) * 2 + 0];
            x1 = meas_xy[(b * N + n) * 2 + 1];
            x2 = meas_v[b * N + n];
            w1 = mp_w1; b1 = mp_b1; w2 = mp_w2; b2 = mp_b2; nin = 3;
            row = b * NS + n;
        } else {
            int b = id - B * N;
            x0 = bs_xy[b * 2 + 0];
            x1 = bs_xy[b * 2 + 1];
            w1 = bp_w1; b1 = bp_b1; w2 = bp_w2; b2 = bp_b2; nin = 2;
            row = b * NS + N;
        }
        float h = x0 * w1[dd] + x1 * w1[D + dd] + b1[dd];
        if (nin == 3) h += x2 * w1[2 * D + dd];
        hid[dd] = gelu_f(h);
        __syncthreads();
        float o = b2[dd];
        for (int j = 0; j < D; j++) o += hid[j] * w2[j * D + dd];
        srcbf[(size_t)row * D + dd] = f2bf(o);
        if (dd == 0) { src_xy[row * 2 + 0] = x0; src_xy[row * 2 + 1] = x1; }
    } else if (bx < 4032) {
        int blk = bx - 3968;
        int b = blk >> 4, kc = blk & 15;
        int k = kc * 256 + tid;
        float* mx = sh; float* my = sh + 512;
        for (int i = tid; i < N; i += 256) {
            mx[i] = meas_xy[(b * N + i) * 2 + 0];
            my[i] = meas_xy[(b * N + i) * 2 + 1];
        }
        __syncthreads();
        float gx = ((k & 63) + 0.5f) / 64.f;
        float gy = ((k >> 6) + 0.5f) / 64.f;
        float s = 0.f;
        for (int n = 0; n < N; n++) {
            float dx = gx - mx[n], dy = gy - my[n];
            s += __expf(-(dx * dx + dy * dy) * 78.125f);
        }
        dens[b * KK + k] = s * (1.f / (float)N);
    } else if (bx < 6080) {
        int i = (bx - 4032) * 256 + tid;
        int x = i & 63, y = (i >> 6) & 63, c = (i >> 12) & 31, b = i >> 17;
        float s = env_b1[c];
        for (int ky = 0; ky < 3; ky++) {
            int yy = y + ky - 1;
            if (yy < 0 || yy >= G) continue;
            for (int kx = 0; kx < 3; kx++) {
                int xx = x + kx - 1;
                if (xx < 0 || xx >= G) continue;
                s += city[(b * CITY + yy * 4) * CITY + xx * 4] * env_w1[c * 9 + ky * 3 + kx];
            }
        }
        h1[i] = gelu_f(s);
    } else if (bx < 6084) {
        int b = bx - 6080;
        float* e = sh;
        e[tid] = task_emb[task_id[b] * D + tid];
        __syncthreads();
        float s = tp_b[tid];
        for (int j = 0; j < D; j++) s += e[j] * tp_w[j * D + tid];
        tvec[b * D + tid] = s;
    } else {
        int bh = bx - 6084;     // 0..31
        unsigned short* kp = khd + ((size_t)bh * 544 + 513) * 32;
        for (int i = tid; i < 992; i += 256) kp[i] = 0;
        unsigned short* vp = vch + ((size_t)bh * 17 + 16) * 1024;
        for (int i = tid; i < 1024; i += 256) vp[i] = 0;
    }
}

// ================= conv2: branchless, 4 c_out/thread, ci-pipelined =================
__global__ __launch_bounds__(256) void conv2_k(
    const float* __restrict__ h1, const float* __restrict__ w,
    const float* __restrict__ bias, float* __restrict__ h2) {
    int blk = blockIdx.x;
    int yt = blk & 15, cg = (blk >> 4) & 7, b = blk >> 7;
    int x = threadIdx.x & 63, y = yt * 4 + (threadIdx.x >> 6);
    int c0 = cg * 4;
    float flag[9];
    int off[9];
    #pragma unroll
    for (int ky = 0; ky < 3; ky++) {
        int yy = y + ky - 1;
        bool vy = (yy >= 0 && yy < G);
        int yc = min(max(yy, 0), G - 1);
        #pragma unroll
        for (int kx = 0; kx < 3; kx++) {
            int xx = x + kx - 1;
            bool vx = (xx >= 0 && xx < G);
            int xc = min(max(xx, 0), G - 1);
            flag[ky * 3 + kx] = (vy && vx) ? 1.f : 0.f;
            off[ky * 3 + kx] = yc * G + xc;
        }
    }
    const float* hp = h1 + ((size_t)(b * EC) << 12);
    float acc[4] = {bias[c0], bias[c0 + 1], bias[c0 + 2], bias[c0 + 3]};
    float v[9], nv[9];
    #pragma unroll
    for (int t = 0; t < 9; t++) v[t] = hp[off[t]] * flag[t];
    for (int ci = 0; ci < EC; ci++) {
        if (ci < EC - 1) {
            const float* hn = hp + ((size_t)(ci + 1) << 12);
            #pragma unroll
            for (int t = 0; t < 9; t++) nv[t] = hn[off[t]] * flag[t];
        }
        #pragma unroll
        for (int cc = 0; cc < 4; cc++) {
            const float* wp = w + ((size_t)(c0 + cc) * EC + ci) * 9;
            #pragma unroll
            for (int t = 0; t < 9; t++) acc[cc] += v[t] * wp[t];
        }
        #pragma unroll
        for (int t = 0; t < 9; t++) v[t] = nv[t];
    }
    size_t obase = (((size_t)(b * EC + c0)) << 12) + y * G + x;
    #pragma unroll
    for (int cc = 0; cc < 4; cc++)
        h2[obase + ((size_t)cc << 12)] = gelu_f(acc[cc]);
}

// ================= pre2: grid_init + out_init (nd bias computed in attn) =================
__global__ __launch_bounds__(256) void pre2_k(
    const float* __restrict__ h2, const float* __restrict__ w3,
    const float* __restrict__ b3, const float* __restrict__ grid_pos,
    const float* __restrict__ tvec, float* __restrict__ grid,
    float* __restrict__ out, const float* __restrict__ head_b)
{
    __shared__ float sh[1088];
    int bx = blockIdx.x;
    int tid = threadIdx.x;
    if (bx < 2048) {
        int b = bx >> 9, k0 = (bx & 511) * 8;
        float (*h2s)[8] = (float (*)[8])sh;
        h2s[tid >> 3][tid & 7] = h2[(((size_t)b * EC + (tid >> 3)) << 12) + k0 + (tid & 7)];
        float w3r[32];
        #pragma unroll
        for (int c4 = 0; c4 < 8; c4++) {
            float4 w4 = *(const float4*)(w3 + tid * 32 + c4 * 4);
            w3r[c4 * 4 + 0] = w4.x; w3r[c4 * 4 + 1] = w4.y;
            w3r[c4 * 4 + 2] = w4.z; w3r[c4 * 4 + 3] = w4.w;
        }
        float base = b3[tid] + tvec[b * D + tid];
        __syncthreads();
        #pragma unroll
        for (int j = 0; j < 8; j++) {
            float s = base + grid_pos[(size_t)(k0 + j) * D + tid];
            #pragma unroll
            for (int ci = 0; ci < 32; ci++) s += h2s[ci][j] * w3r[ci];
            grid[((size_t)b * KK + k0 + j) * D + tid] = s;
        }
    } else {
        out[(bx - 2048) * 256 + tid] = head_b[0];
    }
}

// ================= fused density-inject + layernorm -> bf16 =================
template <int DENS>
__global__ __launch_bounds__(256) void dens_ln_k(
    float* __restrict__ grid, const float* __restrict__ dens,
    const float* __restrict__ dw, const float* __restrict__ db,
    const float* __restrict__ lw, const float* __restrict__ lb,
    unsigned short* __restrict__ y) {
    int row = blockIdx.x * 4 + (threadIdx.x >> 6);
    int lane = threadIdx.x & 63;
    float* gp = grid + (size_t)row * D + lane * 4;
    float4 v = *(float4*)gp;
    if (DENS) {
        float de = dens[row];
        float4 w4 = *(const float4*)(dw + lane * 4);
        float4 b4 = *(const float4*)(db + lane * 4);
        v.x += de * w4.x + b4.x; v.y += de * w4.y + b4.y;
        v.z += de * w4.z + b4.z; v.w += de * w4.w + b4.w;
        *(float4*)gp = v;
    }
    float s = v.x + v.y + v.z + v.w;
    #pragma unroll
    for (int o = 32; o > 0; o >>= 1) s += __shfl_xor(s, o);
    float mean = s * (1.f / D);
    float cx = v.x - mean, cy = v.y - mean, cz = v.z - mean, cw = v.w - mean;
    float q = cx * cx + cy * cy + cz * cz + cw * cw;
    #pragma unroll
    for (int o = 32; o > 0; o >>= 1) q += __shfl_xor(q, o);
    float inv = rsqrtf(q * (1.f / D) + 1e-5f);
    float4 lwv = *(const float4*)(lw + lane * 4);
    float4 lbv = *(const float4*)(lb + lane * 4);
    ushort4 o4;
    o4.x = f2bf(cx * inv * lwv.x + lbv.x);
    o4.y = f2bf(cy * inv * lwv.y + lbv.y);
    o4.z = f2bf(cz * inv * lwv.z + lbv.z);
    o4.w = f2bf(cw * inv * lwv.w + lbv.w);
    *(ushort4*)(y + (size_t)row * D + lane * 4) = o4;
}

// ================= GEMM core (BM=64): C[M,N] = A[M,K] @ Wt[N,K]^T + bias =================
// BM=64, BN=64, BK=64, double-buffered LDS. Used for the small KV projection.
// LDS bank-balance swizzle (both-sides-or-neither): staging lane loads global 16B
// column-group (tid&3)^((tid>>3)&3); reads XOR q4 with ((lr>>1)&3).
template <int GELU, int ACCUM, int OBF, int TFPH, int STBF, int KVT = 0>
__device__ __forceinline__ void gemm_core(
    const unsigned short* __restrict__ A, const unsigned short* __restrict__ Wt,
    const float* __restrict__ bias, void* __restrict__ Cv,
    int M, int K, int Nn, int bn, int bm,
    const float* __restrict__ hw, unsigned short* __restrict__ Xb, float scale,
    unsigned short* As, unsigned short* Bs) {
    int tid = threadIdx.x;
    int wave = tid >> 6, lane = tid & 63;
    int q4 = lane >> 4, lr = lane & 15;
    int wn = wave * 16;
    int srow = tid >> 2;
    int sk8 = ((tid & 3) ^ ((tid >> 3) & 3)) * 8;   // swizzled source column-group
    const unsigned short* Ap  = A  + (size_t)(bm + srow) * K + sk8;
    const unsigned short* Bp0 = Wt + (size_t)(bn + srow) * K + sk8;
    unsigned short* AsD = As + tid * 8;
    unsigned short* BsD = Bs + tid * 8;
    int q4x = (q4 ^ ((lr >> 1) & 3)) * 8;           // swizzled read column-group
    f32x4 acc[4] = {};

    gl2lds16(Ap,       AsD);
    gl2lds16(Ap + 32,  AsD + 2048);
    gl2lds16(Bp0,      BsD);
    gl2lds16(Bp0 + 32, BsD + 2048);

    int nk = K >> 6;
    for (int ki = 0; ki < nk; ki++) {
        __syncthreads();
        if (ki + 1 < nk) {
            int k0 = (ki + 1) << 6;
            int nb = ((ki + 1) & 1) * 4096;
            gl2lds16(Ap + k0,       AsD + nb);
            gl2lds16(Ap + k0 + 32,  AsD + nb + 2048);
            gl2lds16(Bp0 + k0,      BsD + nb);
            gl2lds16(Bp0 + k0 + 32, BsD + nb + 2048);
        }
        int cb = (ki & 1) * 4096;
        #pragma unroll
        for (int ks = 0; ks < 2; ks++) {
            bf16x8 af[4], bf;
            #pragma unroll
            for (int i = 0; i < 4; i++)
                af[i] = *(const bf16x8*)&As[cb + ks * 2048 + (i * 16 + lr) * 32 + q4x];
            bf = *(const bf16x8*)&Bs[cb + ks * 2048 + (wn + lr) * 32 + q4x];
            #pragma unroll
            for (int i = 0; i < 4; i++)
                acc[i] = __builtin_amdgcn_mfma_f32_16x16x32_bf16(af[i], bf, acc[i], 0, 0, 0);
        }
    }

    if (KVT) {
        int gc = bn + wn + lr;
        float bv = bias[gc];
        bool isV = gc >= 256;
        #pragma unroll
        for (int i = 0; i < 4; i++) {
            #pragma unroll
            for (int r = 0; r < 4; r++) {
                int gr = bm + i * 16 + q4 * 4 + r;
                if (gr < MSRC) {
                    float v = acc[i][r] + bv;
                    int bb = gr / NS;
                    int tok = gr - bb * NS;
                    if (!isV) {
                        int h = gc >> 5, dh = gc & 31;
                        // permuted K storage: within chunk, token t32 stored at
                        // kk = ((t32&1)<<4) | ((t32>>3)<<2) | ((t32>>1)&3)
                        int t32 = tok & 31;
                        int kkp = ((t32 & 1) << 4) | ((t32 >> 3) << 2) | ((t32 >> 1) & 3);
                        int tokP = (tok & ~31) | kkp;
                        ((unsigned short*)Cv)[(((size_t)(bb * 8 + h) * 544) + tokP) * 32 + dh] = f2bf(v);
                    } else {
                        int gcv = gc - 256;
                        int h = gcv >> 5, dh = gcv & 31;
                        int c = tok >> 5, t32 = tok & 31;
                        Xb[((((size_t)(bb * 8 + h) * 17 + c) * 32 + dh)) * 32 + t32] = f2bf(v);
                    }
                }
            }
        }
        return;
    }

    int gc = bn + wn + lr;
    float bv = bias[gc];
    #pragma unroll
    for (int i = 0; i < 4; i++) {
        #pragma unroll
        for (int r = 0; r < 4; r++) {
            int gr = bm + i * 16 + q4 * 4 + r;
            if (gr < M) {
                float v = (acc[i][r] + bv) * scale;
                if (GELU) v = gelu_f(v);
                size_t idx = (size_t)gr * Nn + gc;
                if (OBF) {
                    ((unsigned short*)Cv)[idx] = f2bf(v);
                } else if (ACCUM) {
                    float nv = ((float*)Cv)[idx] + v;
                    ((float*)Cv)[idx] = nv;
                    if (STBF) Xb[idx] = f2bf(nv);
                } else {
                    ((float*)Cv)[idx] = v;
                }
            }
        }
    }
}

// ================= GEMM BM=128 core: BK=64, double-buffered LDS (48 KB) =================
// Same bank swizzle as gemm_core; per wave 8 row-frags x 1 col-frag.
template <int GELU, int ACCUM, int OBF, int STBF>
__device__ __forceinline__ void gemm128_core(
    const unsigned short* __restrict__ A, const unsigned short* __restrict__ Wt,
    const float* __restrict__ bias, void* __restrict__ Cv,
    int K, int Nn, int bn, int bm, float scale, unsigned short* __restrict__ Xb,
    unsigned short* As, unsigned short* Bs) {
    int tid = threadIdx.x;
    int wave = tid >> 6, lane = tid & 63;
    int q4 = lane >> 4, lr = lane & 15;
    int wn = wave * 16;
    int srow = tid >> 2;
    int sk8 = ((tid & 3) ^ ((tid >> 3) & 3)) * 8;   // swizzled source column-group
    const unsigned short* Ap  = A + (size_t)(bm + srow) * K + sk8;        // rows 0..63
    const unsigned short* Ap2 = Ap + (size_t)64 * K;                      // rows 64..127
    const unsigned short* Bp  = Wt + (size_t)(bn + srow) * K + sk8;
    unsigned short* AsD = As + tid * 8;
    unsigned short* BsD = Bs + tid * 8;
    int q4x = (q4 ^ ((lr >> 1) & 3)) * 8;           // swizzled read column-group
    f32x4 acc[8] = {};

    gl2lds16(Ap,        AsD);            // rows 0-63,   ks0
    gl2lds16(Ap2,       AsD + 2048);     // rows 64-127, ks0
    gl2lds16(Ap + 32,   AsD + 4096);     // rows 0-63,   ks1
    gl2lds16(Ap2 + 32,  AsD + 6144);     // rows 64-127, ks1
    gl2lds16(Bp,        BsD);
    gl2lds16(Bp + 32,   BsD + 2048);

    int nk = K >> 6;
    for (int ki = 0; ki < nk; ki++) {
        __syncthreads();
        if (ki + 1 < nk) {
            int k0 = (ki + 1) << 6;
            int nbA = ((ki + 1) & 1) * 8192;
            int nbB = ((ki + 1) & 1) * 4096;
            gl2lds16(Ap + k0,        AsD + nbA);
            gl2lds16(Ap2 + k0,       AsD + nbA + 2048);
            gl2lds16(Ap + k0 + 32,   AsD + nbA + 4096);
            gl2lds16(Ap2 + k0 + 32,  AsD + nbA + 6144);
            gl2lds16(Bp + k0,        BsD + nbB);
            gl2lds16(Bp + k0 + 32,   BsD + nbB + 2048);
        }
        int cbA = (ki & 1) * 8192, cbB = (ki & 1) * 4096;
        #pragma unroll
        for (int ks = 0; ks < 2; ks++) {
            bf16x8 bf = *(const bf16x8*)&Bs[cbB + ks * 2048 + (wn + lr) * 32 + q4x];
            #pragma unroll
            for (int i = 0; i < 8; i++) {
                bf16x8 af = *(const bf16x8*)&As[cbA + ks * 4096 + (i * 16 + lr) * 32 + q4x];
                acc[i] = __builtin_amdgcn_mfma_f32_16x16x32_bf16(af, bf, acc[i], 0, 0, 0);
            }
        }
    }

    int gc = bn + wn + lr;
    float bv = bias[gc];
    #pragma unroll
    for (int i = 0; i < 8; i++) {
        #pragma unroll
        for (int r = 0; r < 4; r++) {
            int gr = bm + i * 16 + q4 * 4 + r;
            float v = (acc[i][r] + bv) * scale;
            if (GELU) v = gelu_f(v);
            size_t idx = (size_t)gr * Nn + gc;
            if (OBF) {
                ((unsigned short*)Cv)[idx] = f2bf(v);
            } else if (ACCUM) {
                float nv = ((float*)Cv)[idx] + v;
                ((float*)Cv)[idx] = nv;
                if (STBF) Xb[idx] = f2bf(nv);
            } else {
                ((float*)Cv)[idx] = v;
            }
        }
    }
}

// 1D grid + bijective XCD swizzle (nwg % 8 == 0): each XCD owns a contiguous chunk of
// bm-stripes so the A panel shared by the nx bn-blocks of a stripe is fetched by ONE
// XCD's L2 instead of all 8.
template <int GELU, int ACCUM, int OBF, int STBF>
__global__ __launch_bounds__(256) void gemm128_k(
    const unsigned short* __restrict__ A, const unsigned short* __restrict__ Wt,
    const float* __restrict__ bias, void* __restrict__ Cv,
    int M, int K, int Nn, int nx, float scale, unsigned short* __restrict__ Xb) {
    __shared__ unsigned short As[16384];
    __shared__ unsigned short Bs[8192];
    int nwg = gridDim.x;
    int bid = blockIdx.x;
    int wgid = (bid & 7) * (nwg >> 3) + (bid >> 3);   // XCD-chunked remap (bijective)
    int bn = (wgid % nx) * 64;
    int bm = (wgid / nx) * 128;
    gemm128_core<GELU, ACCUM, OBF, STBF>(A, Wt, bias, Cv, K, Nn, bn, bm, scale, Xb, As, Bs);
}

// ================= fused Q (BM=128) + KV (BM=64) projections, one launch ==============
// Blocks 0..511: Q with XCD swizzle (identical to gemm128_k<0,0,1,0> nx=4, nwg=512).
// Blocks 512..783: KV projection (8 bn x 34 bm), same math as the old kv_k.
__global__ __launch_bounds__(256) void qkv128_k(
    const unsigned short* __restrict__ xbf, const unsigned short* __restrict__ wqT,
    const float* __restrict__ bq, unsigned short* __restrict__ qbf,
    const unsigned short* __restrict__ srcbf, const unsigned short* __restrict__ kvT,
    const float* __restrict__ kvb, unsigned short* __restrict__ khd,
    unsigned short* __restrict__ vch) {
    __shared__ unsigned short As[16384];
    __shared__ unsigned short Bs[8192];
    int bid = blockIdx.x;
    if (bid < 512) {
        int wgid = (bid & 7) * 64 + (bid >> 3);
        int bn = (wgid & 3) * 64;
        int bm = (wgid >> 2) * 128;
        gemm128_core<0, 0, 1, 0>(xbf, wqT, bq, qbf, D, D, bn, bm,
                                 ISQ * LOG2E, nullptr, As, Bs);
    } else {
        int idx = bid - 512;          // 0..271 = 8 bn x 34 bm
        gemm_core<0, 0, 1, 0, 0, 1>(srcbf, kvT, kvb, khd, MSRC, D, 512,
                                    (idx & 7) * 64, (idx >> 3) * 64, nullptr, vch, 1.f, As, Bs);
    }
}

// ================= tfp head GEMM, BM=128: per-task weights + gelu + head-dot epilogue ========
// Same 1D grid + XCD swizzle as gemm128_k (nx = 4).
__global__ __launch_bounds__(256) void tfp128_k(
    const unsigned short* __restrict__ A, const unsigned short* __restrict__ Wt0,
    const float* __restrict__ bias0, float* __restrict__ Cv,
    const int* __restrict__ task_id, const float* __restrict__ hw) {
    __shared__ unsigned short As[16384];
    __shared__ unsigned short Bs[8192];
    int nwg = gridDim.x;
    int bid = blockIdx.x;
    int wgid = (bid & 7) * (nwg >> 3) + (bid >> 3);
    int bn = (wgid & 3) * 64;
    int bm = (wgid >> 2) * 128;
    int tid = threadIdx.x;
    int wave = tid >> 6, lane = tid & 63;
    int q4 = lane >> 4, lr = lane & 15;
    int wn = wave * 16;
    int t = task_id[bm >> 12];
    const unsigned short* Wt = Wt0 + (size_t)t * D * D;
    const float* bias = bias0 + t * D;
    int srow = tid >> 2;
    int sk8 = ((tid & 3) ^ ((tid >> 3) & 3)) * 8;
    const unsigned short* Ap  = A + (size_t)(bm + srow) * D + sk8;
    const unsigned short* Ap2 = Ap + (size_t)64 * D;
    const unsigned short* Bp  = Wt + (size_t)(bn + srow) * D + sk8;
    unsigned short* AsD = As + tid * 8;
    unsigned short* BsD = Bs + tid * 8;
    int q4x = (q4 ^ ((lr >> 1) & 3)) * 8;
    f32x4 acc[8] = {};

    gl2lds16(Ap,        AsD);
    gl2lds16(Ap2,       AsD + 2048);
    gl2lds16(Ap + 32,   AsD + 4096);
    gl2lds16(Ap2 + 32,  AsD + 6144);
    gl2lds16(Bp,        BsD);
    gl2lds16(Bp + 32,   BsD + 2048);

    int nk = D >> 6;
    for (int ki = 0; ki < nk; ki++) {
        __syncthreads();
        if (ki + 1 < nk) {
            int k0 = (ki + 1) << 6;
            int nbA = ((ki + 1) & 1) * 8192;
            int nbB = ((ki + 1) & 1) * 4096;
            gl2lds16(Ap + k0,        AsD + nbA);
            gl2lds16(Ap2 + k0,       AsD + nbA + 2048);
            gl2lds16(Ap + k0 + 32,   AsD + nbA + 4096);
            gl2lds16(Ap2 + k0 + 32,  AsD + nbA + 6144);
            gl2lds16(Bp + k0,        BsD + nbB);
            gl2lds16(Bp + k0 + 32,   BsD + nbB + 2048);
        }
        int cbA = (ki & 1) * 8192, cbB = (ki & 1) * 4096;
        #pragma unroll
        for (int ks = 0; ks < 2; ks++) {
            bf16x8 bf = *(const bf16x8*)&Bs[cbB + ks * 2048 + (wn + lr) * 32 + q4x];
            #pragma unroll
            for (int i = 0; i < 8; i++) {
                bf16x8 af = *(const bf16x8*)&As[cbA + ks * 4096 + (i * 16 + lr) * 32 + q4x];
                acc[i] = __builtin_amdgcn_mfma_f32_16x16x32_bf16(af, bf, acc[i], 0, 0, 0);
            }
        }
    }

    int gc = bn + wn + lr;
    float bv = bias[gc];
    float hv = hw[gc];
    #pragma unroll
    for (int i = 0; i < 8; i++) {
        #pragma unroll
        for (int r = 0; r < 4; r++) {
            float s = gelu_f(acc[i][r] + bv) * hv;
            s += __shfl_xor(s, 1); s += __shfl_xor(s, 2);
            s += __shfl_xor(s, 4); s += __shfl_xor(s, 8);
            if (lr == 0)
                atomicAdd(Cv + (bm + i * 16 + q4 * 4 + r), s);
        }
    }
}

// ================= MFMA flash cross-attention: qt-QUAD per block, shared K/V =========
// S' = K Q^T (query=col, q pre-scaled isq*log2e), p = exp2(s - dist'); O^T = V^T P'.
// K chunk rows are permuted so the S' C/D layout IS the PV B-operand layout (no cross-lane).
// One block = (b, h, qt-quad): rows qt0..qt0+3 SHARE the K/V fragments (K/V L2 traffic per
// query halves vs qt-pair; per-block K/V bytes unchanged - the R7-validated scaling axis).
// LDB stores per-token (dx^2, y*log2e); each row computes sqrt(fma(dy,dy,dx2)). Rows are
// processed sequentially inside BODY to bound transient VGPR; 4 independent chains give ILP.
// 2-deep register prefetch, stages X/Y.
__global__ __launch_bounds__(256) void attn_mfma(
    const unsigned short* __restrict__ qb,
    const unsigned short* __restrict__ khd,
    const unsigned short* __restrict__ vch,
    const float* __restrict__ sxy,
    unsigned short* __restrict__ out)
{
    __shared__ float2 sxys[NSP];
    int bid = blockIdx.x;                    // b*128 + h*16 + qq
    int qq = bid & 15, h = (bid >> 4) & 7, b = bid >> 7;
    int qt0 = qq * 4;
    int tid = threadIdx.x, wave = tid >> 6, lane = tid & 63;
    int q4 = lane >> 4, lr = lane & 15;

    int cell0 = qt0 * 64 + wave * 16 + lr;           // query grid cell, row qt0
    size_t qrow0 = (size_t)(b * KK + cell0);
    bf16x8 qfa = *(const bf16x8*)(qb + qrow0 * D + h * DH + q4 * 8);
    bf16x8 qfb = *(const bf16x8*)(qb + (qrow0 + 64) * D + h * DH + q4 * 8);
    bf16x8 qfc = *(const bf16x8*)(qb + (qrow0 + 128) * D + h * DH + q4 * 8);
    bf16x8 qfd = *(const bf16x8*)(qb + (qrow0 + 192) * D + h * DH + q4 * 8);
    const unsigned short* kp0 = khd + ((size_t)(b * 8 + h) * 544) * 32 + lr * 32 + q4 * 8;
    const unsigned short* vb0 = vch + ((size_t)(b * 8 + h) * 17) * 1024 + lr * 32 + q4 * 8;

    float lla = 0.f, llb = 0.f, llc = 0.f, lld = 0.f;
    f32x4 o0a = {0.f,0.f,0.f,0.f}, o1a = {0.f,0.f,0.f,0.f};
    f32x4 o0b = {0.f,0.f,0.f,0.f}, o1b = {0.f,0.f,0.f,0.f};
    f32x4 o0c = {0.f,0.f,0.f,0.f}, o1c = {0.f,0.f,0.f,0.f};
    f32x4 o0d = {0.f,0.f,0.f,0.f}, o1d = {0.f,0.f,0.f,0.f};

    bf16x8 k0X, k1X, v0X, v1X, k0Y, k1Y, v0Y, v1Y;
    f32x4 x20X, x21X, ey0X, ey1X;   // per-token dx^2 and y*log2e (even/odd slots), stage X
    f32x4 x20Y, x21Y, ey0Y, ey1Y;   // stage Y

#define LDK(S, c) { size_t co = (size_t)(c) * 1024; \
    k0##S = *(const bf16x8*)(kp0 + co); k1##S = *(const bf16x8*)(kp0 + co + 512); }
#define LDV(S, c) { size_t co = (size_t)(c) * 1024; \
    v0##S = *(const bf16x8*)(vb0 + co); v1##S = *(const bf16x8*)(vb0 + co + 512); }

    // issue global K/V prefetch before LDS staging so HBM latency overlaps it
    LDK(X, 0); LDV(X, 0);
    LDK(Y, 1); LDV(Y, 1);

    // stage (x*log2e, y*log2e); pads -> huge dist -> p = 0
    const float2* sb = (const float2*)(sxy + 2 * (size_t)b * NS);
    for (int i = tid; i < NSP; i += 256) {
        float2 v = (i < NS) ? sb[i] : make_float2(1.e4f, 1.e4f);
        sxys[i] = make_float2(v.x * LOG2E, v.y * LOG2E);
    }
    __syncthreads();

    int qi = wave * 16 + lr;                         // query x-cell (shared by all 4 rows)
    float gxp  = (qi + 0.5f) * (1.f / 64.f) * LOG2E;
    float gy0p = (qt0 + 0.5f) * (1.f / 64.f) * LOG2E;
    float gy1p = (qt0 + 1.5f) * (1.f / 64.f) * LOG2E;
    float gy2p = (qt0 + 2.5f) * (1.f / 64.f) * LOG2E;
    float gy3p = (qt0 + 3.5f) * (1.f / 64.f) * LOG2E;
    const float2* spf = &sxys[q4 * 8];

    // tokens for this lane in chunk c: c*32 + q4*8 + {0..7}; slot r of s0 uses token 2r,
    // slot r of s1 uses token 2r+1 (the K permutation). dx^2 shared by all 4 rows.
#define LDB(S, c) { const float4* p4_ = (const float4*)(spf + (size_t)(c) * 32); \
    float4 a0_ = p4_[0], a1_ = p4_[1], a2_ = p4_[2], a3_ = p4_[3]; \
    float ex_; \
    ex_ = gxp - a0_.x; x20##S[0] = ex_ * ex_; ey0##S[0] = a0_.y; \
    ex_ = gxp - a0_.z; x21##S[0] = ex_ * ex_; ey1##S[0] = a0_.w; \
    ex_ = gxp - a1_.x; x20##S[1] = ex_ * ex_; ey0##S[1] = a1_.y; \
    ex_ = gxp - a1_.z; x21##S[1] = ex_ * ex_; ey1##S[1] = a1_.w; \
    ex_ = gxp - a2_.x; x20##S[2] = ex_ * ex_; ey0##S[2] = a2_.y; \
    ex_ = gxp - a2_.z; x21##S[2] = ex_ * ex_; ey1##S[2] = a2_.w; \
    ex_ = gxp - a3_.x; x20##S[3] = ex_ * ex_; ey0##S[3] = a3_.y; \
    ex_ = gxp - a3_.z; x21##S[3] = ex_ * ex_; ey1##S[3] = a3_.w; }

    LDB(X, 0); LDB(Y, 1);

#define DEXP(s_, x2_, ey_, gyr) ({ float dy_ = (gyr) - (ey_); \
    __builtin_amdgcn_exp2f((s_) - __builtin_amdgcn_sqrtf(__builtin_fmaf(dy_, dy_, (x2_)))); })

    // one query row: QK MFMA pair -> softmax numerators -> PV MFMA pair
#define ROW(S, r, gyr) { \
    f32x4 s0_ = {0.f,0.f,0.f,0.f}, s1_ = {0.f,0.f,0.f,0.f}; \
    s0_ = __builtin_amdgcn_mfma_f32_16x16x32_bf16(k0##S, qf##r, s0_, 0, 0, 0); \
    s1_ = __builtin_amdgcn_mfma_f32_16x16x32_bf16(k1##S, qf##r, s1_, 0, 0, 0); \
    float p0_[4], p1_[4]; \
    p0_[0] = DEXP(s0_[0], x20##S[0], ey0##S[0], gyr); \
    p0_[1] = DEXP(s0_[1], x20##S[1], ey0##S[1], gyr); \
    p0_[2] = DEXP(s0_[2], x20##S[2], ey0##S[2], gyr); \
    p0_[3] = DEXP(s0_[3], x20##S[3], ey0##S[3], gyr); \
    p1_[0] = DEXP(s1_[0], x21##S[0], ey1##S[0], gyr); \
    p1_[1] = DEXP(s1_[1], x21##S[1], ey1##S[1], gyr); \
    p1_[2] = DEXP(s1_[2], x21##S[2], ey1##S[2], gyr); \
    p1_[3] = DEXP(s1_[3], x21##S[3], ey1##S[3], gyr); \
    ll##r += ((p0_[0] + p0_[1]) + (p0_[2] + p0_[3])) + ((p1_[0] + p1_[1]) + (p1_[2] + p1_[3])); \
    union { unsigned u[4]; bf16x8 v; } pu_; \
    pu_.u[0] = cvtpk(p0_[0], p1_[0]); \
    pu_.u[1] = cvtpk(p0_[1], p1_[1]); \
    pu_.u[2] = cvtpk(p0_[2], p1_[2]); \
    pu_.u[3] = cvtpk(p0_[3], p1_[3]); \
    o0##r = __builtin_amdgcn_mfma_f32_16x16x32_bf16(v0##S, pu_.v, o0##r, 0, 0, 0); \
    o1##r = __builtin_amdgcn_mfma_f32_16x16x32_bf16(v1##S, pu_.v, o1##r, 0, 0, 0); \
}

#define BODY(S, cp) { \
    ROW(S, a, gy0p); \
    ROW(S, b, gy1p); \
    ROW(S, c, gy2p); \
    ROW(S, d, gy3p); \
    LDK(S, cp); \
    LDB(S, cp); \
    LDV(S, cp); \
}

    for (int cc = 0; cc < 16; cc += 2) {
        int cpX = cc + 2;                       // cc <= 14 -> cpX <= 16, always valid
        int cpY = (cc + 3 > 16) ? 16 : cc + 3;  // clamp; redundant reload is harmless
        BODY(X, cpX);
        BODY(Y, cpY);
    }
    BODY(X, 16);   // chunk 16 tail; trailing prefetch is dead and DCE'd

#undef BODY
#undef ROW
#undef DEXP
#undef LDB
#undef LDK
#undef LDV

#define FINROW(r, rowoff) { \
    float ll_ = ll##r; \
    ll_ += __shfl_xor(ll_, 16); \
    ll_ += __shfl_xor(ll_, 32); \
    float inv_ = 1.f / ll_; \
    uint2 s0_, s1_; \
    s0_.x = cvtpk(o0##r[0] * inv_, o0##r[1] * inv_); \
    s0_.y = cvtpk(o0##r[2] * inv_, o0##r[3] * inv_); \
    s1_.x = cvtpk(o1##r[0] * inv_, o1##r[1] * inv_); \
    s1_.y = cvtpk(o1##r[2] * inv_, o1##r[3] * inv_); \
    *(uint2*)(out + (qrow0 + (rowoff)) * D + h * DH + q4 * 4) = s0_; \
    *(uint2*)(out + (qrow0 + (rowoff)) * D + h * DH + 16 + q4 * 4) = s1_; \
}
    FINROW(a, 0);
    FINROW(b, 64);
    FINROW(c, 128);
    FINROW(d, 192);
#undef FINROW
}

extern "C" void kernel_launch(void* const* d_in, const int* in_sizes, int n_in,
                              void* d_out, int out_size, void* d_ws, size_t ws_size,
                              hipStream_t stream) {
    const float* meas_xy = (const float*)d_in[0];
    const float* meas_v  = (const float*)d_in[1];
    const float* bs_xy   = (const float*)d_in[2];
    const int*   task_id = (const int*)d_in[3];
    const float* city    = (const float*)d_in[4];
    const float* mp_w1 = (const float*)d_in[5];  const float* mp_b1 = (const float*)d_in[6];
    const float* mp_w2 = (const float*)d_in[7];  const float* mp_b2 = (const float*)d_in[8];
    const float* bp_w1 = (const float*)d_in[9];  const float* bp_b1 = (const float*)d_in[10];
    const float* bp_w2 = (const float*)d_in[11]; const float* bp_b2 = (const float*)d_in[12];
    const float* env_w1 = (const float*)d_in[13]; const float* env_b1 = (const float*)d_in[14];
    const float* env_w2 = (const float*)d_in[15]; const float* env_b2 = (const float*)d_in[16];
    const float* env_w3 = (const float*)d_in[17]; const float* env_b3 = (const float*)d_in[18];
    const float* task_emb = (const float*)d_in[19];
    const float* tp_w = (const float*)d_in[20]; const float* tp_b = (const float*)d_in[21];
    const float* grid_pos = (const float*)d_in[22];
    const float* dens_w = (const float*)d_in[23]; const float* dens_b = (const float*)d_in[24];
    const float* ln1_w = (const float*)d_in[25]; const float* ln1_b = (const float*)d_in[26];
    const float* wq = (const float*)d_in[27]; const float* bq = (const float*)d_in[28];
    const float* wk = (const float*)d_in[29]; const float* bk = (const float*)d_in[30];
    const float* wv = (const float*)d_in[31]; const float* bv = (const float*)d_in[32];
    const float* wo = (const float*)d_in[33]; const float* bo = (const float*)d_in[34];
    const float* ln2_w = (const float*)d_in[35]; const float* ln2_b = (const float*)d_in[36];
    const float* ff_w1 = (const float*)d_in[37]; const float* ff_b1 = (const float*)d_in[38];
    const float* ff_w2 = (const float*)d_in[39]; const float* ff_b2 = (const float*)d_in[40];
    const float* tfp_w = (const float*)d_in[41]; const float* tfp_b = (const float*)d_in[42];
    const float* head_w = (const float*)d_in[43]; const float* head_b = (const float*)d_in[44];
    float* out = (float*)d_out;

    float* ws = (float*)d_ws;
    size_t off = 0;
    float* src_xy = ws + off; off += (size_t)B * NS * 2 + 128;
    float* dens   = ws + off; off += (size_t)B * KK;
    float* tvec   = ws + off; off += (size_t)B * D;
    float* h1     = ws + off; off += (size_t)B * EC * KK;
    float* grid   = ws + off; off += (size_t)B * KK * D;
    unsigned short* srcbf = (unsigned short*)(ws + off); off += (size_t)MSRCP * D / 2;
    unsigned short* khd   = (unsigned short*)(ws + off); off += (size_t)B * 8 * 544 * 32 / 2;
    unsigned short* vch   = (unsigned short*)(ws + off); off += (size_t)B * 8 * 17 * 1024 / 2;
    float* qreg   = ws + off; off += (size_t)B * KK * D / 2;   // qbf; hosts h2 f32 early
    unsigned short* qbf = (unsigned short*)qreg;
    float* h2     = qreg;
    unsigned short* xbf    = (unsigned short*)(ws + off); off += (size_t)B * KK * D / 2;
    unsigned short* attnbf = (unsigned short*)(ws + off); off += (size_t)B * KK * D / 2;
    unsigned short* hidbf  = (unsigned short*)(ws + off); off += (size_t)B * KK * DFF / 2;    // 32 MB
    unsigned short* wqT  = (unsigned short*)(ws + off); off += (size_t)LYR * D * D / 2;
    unsigned short* kvT  = (unsigned short*)(ws + off); off += (size_t)LYR * 512 * D / 2;
    unsigned short* woT  = (unsigned short*)(ws + off); off += (size_t)LYR * D * D / 2;
    unsigned short* ff1T = (unsigned short*)(ws + off); off += (size_t)LYR * D * DFF / 2;
    unsigned short* ff2T = (unsigned short*)(ws + off); off += (size_t)LYR * DFF * D / 2;
    unsigned short* tfpT = (unsigned short*)(ws + off); off += (size_t)T * D * D / 2;
    float* kvbias = ws + off; off += (size_t)LYR * 512;
    (void)ws_size; (void)n_in; (void)in_sizes; (void)out_size;

    const int M = B * KK;       // 16384

    pre1_k<<<6116, 256, 0, stream>>>(
        wq, wk, wv, wo, ff_w1, ff_w2, tfp_w, bk, bv,
        wqT, kvT, woT, ff1T, ff2T, tfpT, kvbias,
        meas_xy, meas_v, bs_xy, mp_w1, mp_b1, mp_w2, mp_b2,
        bp_w1, bp_b1, bp_w2, bp_b2, srcbf, src_xy,
        dens, city, env_w1, env_b1, h1,
        task_emb, task_id, tp_w, tp_b, tvec, khd, vch);
    conv2_k<<<512, 256, 0, stream>>>(h1, env_w2, env_b2, h2);
    pre2_k<<<2112, 256, 0, stream>>>(h2, env_w3, env_b3, grid_pos, tvec, grid,
                                     out, head_b);

    for (int l = 0; l < LYR; l++) {
        dens_ln_k<1><<<M / 4, 256, 0, stream>>>(grid, dens, dens_w + l * D, dens_b + l * D,
                                                ln1_w + l * D, ln1_b + l * D, xbf);
        qkv128_k<<<784, 256, 0, stream>>>(
            xbf, wqT + (size_t)l * D * D, bq + l * D, qbf,
            srcbf, kvT + (size_t)l * 512 * D, kvbias + l * 512, khd, vch);
        attn_mfma<<<B * NH * 16, 256, 0, stream>>>(qbf, khd, vch, src_xy, attnbf);
        gemm128_k<0, 1, 0, 0><<<512, 256, 0, stream>>>(
            attnbf, woT + (size_t)l * D * D, bo + l * D, grid, M, D, D, 4, 1.f, nullptr);
        dens_ln_k<0><<<M / 4, 256, 0, stream>>>(grid, nullptr, nullptr, nullptr,
                                                ln2_w + l * D, ln2_b + l * D, xbf);
        gemm128_k<1, 0, 1, 0><<<2048, 256, 0, stream>>>(
            xbf, ff1T + (size_t)l * D * DFF, ff_b1 + l * DFF, hidbf, M, D, DFF, 16, 1.f, nullptr);
        if (l == 0) {
            gemm128_k<0, 1, 0, 0><<<512, 256, 0, stream>>>(
                hidbf, ff2T + (size_t)l * DFF * D, ff_b2 + l * D, grid, M, DFF, D, 4, 1.f, nullptr);
        } else {
            gemm128_k<0, 1, 0, 1><<<512, 256, 0, stream>>>(
                hidbf, ff2T + (size_t)l * DFF * D, ff_b2 + l * D, grid, M, DFF, D, 4, 1.f, xbf);
        }
    }
    tfp128_k<<<512, 256, 0, stream>>>(xbf, tfpT, tfp_b, out, task_id, head_w);
}